// Round 6
// baseline (234.438 us; speedup 1.0000x reference)
//
#include <hip/hip_runtime.h>
#include <hip/hip_bf16.h>

typedef _Float16 f16;
typedef _Float16 f16x8 __attribute__((ext_vector_type(8)));
typedef _Float16 f16x4 __attribute__((ext_vector_type(4)));
typedef float f32x4 __attribute__((ext_vector_type(4)));

#define MFMA32(a, b, c) __builtin_amdgcn_mfma_f32_16x16x32_f16(a, b, c, 0, 0, 0)
#define MFMA16(a, b, c) __builtin_amdgcn_mfma_f32_16x16x16f16(a, b, c, 0, 0, 0)

static constexpr int S  = 4096;
static constexpr int NB = 4;    // batches

// ---------------------------------------------------------------------------
// Weight convert + transpose, all four weights in one launch.
// grid 1024: j = bid>>8 selects the weight; Wt[n][k] = (f16) W[k][n].
// ---------------------------------------------------------------------------
__global__ void wconv4_kernel(const float* __restrict__ W0, const float* __restrict__ W1,
                              const float* __restrict__ W2, const float* __restrict__ W3,
                              f16* __restrict__ T0, f16* __restrict__ T1,
                              f16* __restrict__ T2, f16* __restrict__ T3) {
    int j = blockIdx.x >> 8;
    int k = blockIdx.x & 255;
    int n = threadIdx.x;
    const float* W = (j == 0) ? W0 : (j == 1) ? W1 : (j == 2) ? W2 : W3;
    f16*         T = (j == 0) ? T0 : (j == 1) ? T1 : (j == 2) ? T2 : T3;
    T[n * 256 + k] = (f16)W[k * 256 + n];
}

// ---------------------------------------------------------------------------
// Projection GEMM: O[m][n] = epilogue( sum_k A[m][k] * Wt[n][k] + bias[n] )
// M = 16384, N = 256, K = 256.  Block: 256 thr (4 waves), BM = 32 rows/block.
// ASRC: 0 = A is fp32 (convert on the fly), 1 = A is f16.
// OMODE: 0 = store f16 row-major; 1 = cos() then store f16 row-major
// ---------------------------------------------------------------------------
template <int ASRC, int OMODE>
__global__ __launch_bounds__(256) void proj_kernel(
    const float* __restrict__ Af, const f16* __restrict__ Ah,
    const f16* __restrict__ Wt, const float* __restrict__ bias,
    f16* __restrict__ O)
{
    int mbase = blockIdx.x * 32;
    int tid = threadIdx.x;
    int w = tid >> 6, l = tid & 63;
    int lr = l & 15, lg = l >> 4;
    int nbase = w * 64;

    f32x4 acc[2][4];
#pragma unroll
    for (int mf = 0; mf < 2; ++mf)
#pragma unroll
        for (int nf = 0; nf < 4; ++nf) acc[mf][nf] = f32x4{0.f, 0.f, 0.f, 0.f};

#pragma unroll
    for (int ks = 0; ks < 8; ++ks) {
        int kof = ks * 32 + lg * 8;
        f16x8 a[2], b[4];
#pragma unroll
        for (int mf = 0; mf < 2; ++mf) {
            int row = mbase + mf * 16 + lr;
            if (ASRC == 0) {
                const float4* p = (const float4*)(Af + row * 256 + kof);
                float4 x0 = p[0], x1 = p[1];
                f16x8 t;
                t[0] = (f16)x0.x; t[1] = (f16)x0.y; t[2] = (f16)x0.z; t[3] = (f16)x0.w;
                t[4] = (f16)x1.x; t[5] = (f16)x1.y; t[6] = (f16)x1.z; t[7] = (f16)x1.w;
                a[mf] = t;
            } else {
                a[mf] = *(const f16x8*)(Ah + row * 256 + kof);
            }
        }
#pragma unroll
        for (int nf = 0; nf < 4; ++nf) {
            int col = nbase + nf * 16 + lr;
            b[nf] = *(const f16x8*)(Wt + col * 256 + kof);
        }
#pragma unroll
        for (int mf = 0; mf < 2; ++mf)
#pragma unroll
            for (int nf = 0; nf < 4; ++nf)
                acc[mf][nf] = MFMA32(a[mf], b[nf], acc[mf][nf]);
    }

    // C/D layout: col = lane&15, row = (lane>>4)*4 + reg  [HW-verified]
#pragma unroll
    for (int mf = 0; mf < 2; ++mf) {
#pragma unroll
        for (int nf = 0; nf < 4; ++nf) {
            int col = nbase + nf * 16 + lr;
            float bv = bias[col];
#pragma unroll
            for (int r = 0; r < 4; ++r) {
                int row = mbase + mf * 16 + lg * 4 + r;
                float x = acc[mf][nf][r] + bv;
                if (OMODE == 1) x = cosf(x);
                O[row * 256 + col] = (f16)x;
            }
        }
    }
}

// ---------------------------------------------------------------------------
// Fused K+V projection from `value`: 512 thr, waves 0-3 -> K (row-major f16),
// waves 4-7 -> V (transposed f16 per batch: O[(bi*256+n)*S + s]).
// Reads `value` fp32 once (L1 serves the second group).
// ---------------------------------------------------------------------------
__global__ __launch_bounds__(512) void kvproj_kernel(
    const float* __restrict__ Af,
    const f16* __restrict__ WkT, const f16* __restrict__ WvT,
    const float* __restrict__ bk, const float* __restrict__ bv,
    f16* __restrict__ Kf, f16* __restrict__ VtF)
{
    int mbase = blockIdx.x * 32;
    int tid = threadIdx.x;
    int w = tid >> 6, l = tid & 63;
    int lr = l & 15, lg = l >> 4;
    int path = w >> 2;             // 0: K path, 1: V path
    int nbase = (w & 3) * 64;
    const f16* Wt = path ? WvT : WkT;
    const float* bias = path ? bv : bk;

    f32x4 acc[2][4];
#pragma unroll
    for (int mf = 0; mf < 2; ++mf)
#pragma unroll
        for (int nf = 0; nf < 4; ++nf) acc[mf][nf] = f32x4{0.f, 0.f, 0.f, 0.f};

#pragma unroll
    for (int ks = 0; ks < 8; ++ks) {
        int kof = ks * 32 + lg * 8;
        f16x8 a[2], b[4];
#pragma unroll
        for (int mf = 0; mf < 2; ++mf) {
            int row = mbase + mf * 16 + lr;
            const float4* p = (const float4*)(Af + row * 256 + kof);
            float4 x0 = p[0], x1 = p[1];
            f16x8 t;
            t[0] = (f16)x0.x; t[1] = (f16)x0.y; t[2] = (f16)x0.z; t[3] = (f16)x0.w;
            t[4] = (f16)x1.x; t[5] = (f16)x1.y; t[6] = (f16)x1.z; t[7] = (f16)x1.w;
            a[mf] = t;
        }
#pragma unroll
        for (int nf = 0; nf < 4; ++nf) {
            int col = nbase + nf * 16 + lr;
            b[nf] = *(const f16x8*)(Wt + col * 256 + kof);
        }
#pragma unroll
        for (int mf = 0; mf < 2; ++mf)
#pragma unroll
            for (int nf = 0; nf < 4; ++nf)
                acc[mf][nf] = MFMA32(a[mf], b[nf], acc[mf][nf]);
    }

#pragma unroll
    for (int mf = 0; mf < 2; ++mf) {
#pragma unroll
        for (int nf = 0; nf < 4; ++nf) {
            int col = nbase + nf * 16 + lr;
            float bv2 = bias[col];
            if (path == 0) {
#pragma unroll
                for (int r = 0; r < 4; ++r) {
                    int row = mbase + mf * 16 + lg * 4 + r;
                    Kf[row * 256 + col] = (f16)(acc[mf][nf][r] + bv2);
                }
            } else {
                int bi = mbase >> 12;
                int s  = (mbase & (S - 1)) + mf * 16 + lg * 4;
                f16x4 v;
#pragma unroll
                for (int r = 0; r < 4; ++r) v[r] = (f16)(acc[mf][nf][r] + bv2);
                *(f16x4*)(VtF + ((bi * 256 + col) * S + s)) = v;
            }
        }
    }
}

// ---------------------------------------------------------------------------
// Flash attention, 8 waves/block, KBLK = 32, in-tile key split, ONE barrier
// per iteration.
//   Waves 0-3 (g=0): keys 0..15 of each 32-key tile; waves 4-7: keys 16..31.
//   Wave wg owns q-rows qbase + wg*16.  NT = 128 iterations.
//   K-hat [2][32][264] and V^T [2][256][40] both DOUBLE-buffered: iter t reads
//   buf[t&1], commits tile t+1 into buf[t&1^1] BEFORE the single barrier ->
//   all reads of a buffer precede the barrier, all overwrites follow it.
//   P is per-wave LDS (intra-wave dep only, no barrier).  PV uses
//   v_mfma_f32_16x16x16_f16 (K=16, own group's keys only).
//   Softmax: defer-max (thr 8), per-lane partial denom, end-only reduce;
//   cross-group merge via LDS overlay epilogue.
// Grid: 256 blocks.  bid&7 -> XCD; batch b = (bid>>1)&3 pins to 2 XCDs.
// ---------------------------------------------------------------------------
__global__ __launch_bounds__(512, 1) void attn_kernel(
    const f16* __restrict__ Qf, const f16* __restrict__ Hf,
    const f16* __restrict__ Vt, float* __restrict__ Out)
{
    // loop: KhS 2x32x264 (33792) + VtS 2x256x40 (40960) + PS 8x16x20 (5120)
    __shared__ __align__(16) char ldsp[79872];
    f16 (*KhS)[32][264]    = (f16(*)[32][264])ldsp;
    f16 (*VtS)[256][40]    = (f16(*)[256][40])(ldsp + 33792);
    f16 (*PS)[16][20]      = (f16(*)[16][20])(ldsp + 74752);
    float (*MrgF)[16][130] = (float(*)[16][130])ldsp;           // epilogue overlay
    float (*ML)[16][2]     = (float(*)[16][2])(ldsp + 33280);

    int bid = blockIdx.x;
    int b   = (bid >> 1) & 3;
    int qi  = ((bid >> 3) << 1) | (bid & 1);
    int qbase = qi * 64;

    int tid = threadIdx.x;
    int w  = tid >> 6, l = tid & 63;
    int g  = w >> 2, wg = w & 3;
    int lr = l & 15, lg = l >> 4;
    int qb = qbase + wg * 16;
    int kg = g * 16;              // this group's key offset within the 32-key tile

    // staging: 512 thr, 2 x 16B chunks each for K-hat (32x256) and V^T (256x32)
    int krow[2], kc[2], vrow[2], vc[2];
#pragma unroll
    for (int i = 0; i < 2; ++i) {
        int c = i * 512 + tid;
        krow[i] = c >> 5;  kc[i] = c & 31;
        vrow[i] = c >> 2;  vc[i] = c & 3;
    }

    // Q fragments for this wave's 16 rows (registers for all 128 tiles)
    f16x8 qf[8];
    {
        const f16* qp = Qf + (b * S + qb + lr) * 256 + lg * 8;
#pragma unroll
        for (int ks = 0; ks < 8; ++ks) qf[ks] = *(const f16x8*)(qp + ks * 32);
    }

    f32x4 Oacc[16];
#pragma unroll
    for (int i = 0; i < 16; ++i) Oacc[i] = f32x4{0.f, 0.f, 0.f, 0.f};
    float mrun[4], lsum[4];
#pragma unroll
    for (int r = 0; r < 4; ++r) { mrun[r] = -1e30f; lsum[r] = 0.f; }

    const f16* Hbase = Hf + b * S * 256;
    const f16* Vbase = Vt + b * 256 * S;

    // prologue: stage tile 0 into buffer 0 (K-hat and V)
#pragma unroll
    for (int i = 0; i < 2; ++i) {
        *(f16x8*)&KhS[0][krow[i]][kc[i] * 8] =
            *(const f16x8*)(Hbase + krow[i] * 256 + kc[i] * 8);
        *(f16x8*)&VtS[0][vrow[i]][vc[i] * 8] =
            *(const f16x8*)(Vbase + (size_t)vrow[i] * S + vc[i] * 8);
    }
    __syncthreads();

    const int NT = S / 32;     // 128 key-tiles
    for (int t = 0; t < NT; ++t) {
        int cur = t & 1;
        int kt = t * 32;

        // issue tile t+1 loads early (hide HBM/L2 latency under QK+softmax+PV)
        f16x8 rgK[2], rgV[2];
        if (t + 1 < NT) {
#pragma unroll
            for (int i = 0; i < 2; ++i) {
                rgK[i] = *(const f16x8*)(Hbase + (kt + 32 + krow[i]) * 256 + kc[i] * 8);
                rgV[i] = *(const f16x8*)(Vbase + (size_t)vrow[i] * S + kt + 32 + vc[i] * 8);
            }
        }

        // scores: 16 q-rows x this group's 16 keys, K=256
        f32x4 scA = f32x4{0.f,0.f,0.f,0.f}, scB = f32x4{0.f,0.f,0.f,0.f};
        __builtin_amdgcn_s_setprio(1);
#pragma unroll
        for (int ks = 0; ks < 8; ks += 2) {
            f16x8 kb0 = *(const f16x8*)&KhS[cur][kg + lr][ks * 32 + lg * 8];
            f16x8 kb1 = *(const f16x8*)&KhS[cur][kg + lr][(ks + 1) * 32 + lg * 8];
            scA = MFMA32(qf[ks], kb0, scA);
            scB = MFMA32(qf[ks + 1], kb1, scB);
        }
        __builtin_amdgcn_s_setprio(0);
        f32x4 sc = scA + scB;

        // ---- softmax, defer-max: no shuffles/rescale in steady state ----
        int need = 0;
#pragma unroll
        for (int r = 0; r < 4; ++r) need |= (sc[r] > mrun[r] + 8.f) ? 1 : 0;
        if (__any(need)) {        // rare: max grew past threshold
            float corr[4];
#pragma unroll
            for (int r = 0; r < 4; ++r) {
                float mt = sc[r];
#pragma unroll
                for (int msk = 1; msk <= 8; msk <<= 1) mt = fmaxf(mt, __shfl_xor(mt, msk));
                float mn = fmaxf(mrun[r], mt);
                corr[r] = __expf(mrun[r] - mn);
                mrun[r] = mn;
                lsum[r] *= corr[r];
            }
#pragma unroll
            for (int i = 0; i < 16; ++i) {
                f32x4 o = Oacc[i];
                o[0] *= corr[0]; o[1] *= corr[1]; o[2] *= corr[2]; o[3] *= corr[3];
                Oacc[i] = o;
            }
        }
#pragma unroll
        for (int r = 0; r < 4; ++r) {
            float p = __expf(sc[r] - mrun[r]);   // bounded by e^8
            lsum[r] += p;
            PS[w][lg * 4 + r][lr] = (f16)p;
        }

        // ---- PV: Oacc[q][d] += P[q][key] * V^T[d][key], own 16 keys ----
        {
            f16x4 pa = *(const f16x4*)&PS[w][lr][lg * 4];   // intra-wave LDS dep
            __builtin_amdgcn_s_setprio(1);
#pragma unroll
            for (int nf2 = 0; nf2 < 16; ++nf2) {
                f16x4 vb = *(const f16x4*)&VtS[cur][nf2 * 16 + lr][kg + lg * 4];
                Oacc[nf2] = MFMA16(pa, vb, Oacc[nf2]);
            }
            __builtin_amdgcn_s_setprio(0);
        }

        // commit tile t+1 into the other buffer, then the single barrier
        if (t + 1 < NT) {
#pragma unroll
            for (int i = 0; i < 2; ++i) {
                *(f16x8*)&KhS[cur ^ 1][krow[i]][kc[i] * 8] = rgK[i];
                *(f16x8*)&VtS[cur ^ 1][vrow[i]][vc[i] * 8] = rgV[i];
            }
        }
        __syncthreads();
    }

    // ---- epilogue: reduce denominators, merge the two key-groups ----
    float lrun[4];
#pragma unroll
    for (int r = 0; r < 4; ++r) {
        float s = lsum[r];
#pragma unroll
        for (int msk = 1; msk <= 8; msk <<= 1) s += __shfl_xor(s, msk);
        lrun[r] = s;
    }
    __syncthreads();              // loop LDS dead; safe to overlay

    if (lr == 0) {
#pragma unroll
        for (int r = 0; r < 4; ++r) {
            ML[w][lg * 4 + r][0] = mrun[r];
            ML[w][lg * 4 + r][1] = lrun[r];
        }
    }
    __syncthreads();

    float partM[4], partL[4];
#pragma unroll
    for (int r = 0; r < 4; ++r) {
        partM[r] = ML[w ^ 4][lg * 4 + r][0];
        partL[r] = ML[w ^ 4][lg * 4 + r][1];
    }
    float w0[4], w1[4];   // g0: w0 = e0*invd, w1 = invd.   g1: w1 = e1.
    if (g == 0) {
#pragma unroll
        for (int r = 0; r < 4; ++r) {
            float m  = fmaxf(mrun[r], partM[r]);
            float e0 = __expf(mrun[r] - m);
            float e1 = __expf(partM[r] - m);
            float invd = 1.0f / (lrun[r] * e0 + partL[r] * e1);
            w0[r] = e0 * invd;
            w1[r] = invd;
        }
    } else {
#pragma unroll
        for (int r = 0; r < 4; ++r) {
            float m = fmaxf(mrun[r], partM[r]);
            w1[r] = __expf(mrun[r] - m);
        }
    }

#pragma unroll
    for (int p = 0; p < 2; ++p) {
        if (g == 1) {
#pragma unroll
            for (int h = 0; h < 8; ++h) {
                int nf2 = p * 8 + h;
#pragma unroll
                for (int r = 0; r < 4; ++r)
                    MrgF[wg][lg * 4 + r][h * 16 + lr] = Oacc[nf2][r] * w1[r];
            }
        }
        __syncthreads();
        if (g == 0) {
#pragma unroll
            for (int h = 0; h < 8; ++h) {
                int nf2 = p * 8 + h;
#pragma unroll
                for (int r = 0; r < 4; ++r) {
                    float v = MrgF[wg][lg * 4 + r][h * 16 + lr];
                    int row = qb + lg * 4 + r;
                    Out[(b * S + row) * 256 + nf2 * 16 + lr] =
                        Oacc[nf2][r] * w0[r] + v * w1[r];
                }
            }
        }
        __syncthreads();
    }
}

// ---------------------------------------------------------------------------
extern "C" void kernel_launch(void* const* d_in, const int* in_sizes, int n_in,
                              void* d_out, int out_size, void* d_ws, size_t ws_size,
                              hipStream_t stream)
{
    const float* query = (const float*)d_in[0];
    const float* value = (const float*)d_in[1];
    const float* Wq    = (const float*)d_in[2];
    const float* bq    = (const float*)d_in[3];
    const float* Wk    = (const float*)d_in[4];
    const float* bk    = (const float*)d_in[5];
    const float* Wv    = (const float*)d_in[6];
    const float* bv    = (const float*)d_in[7];
    const float* Wr    = (const float*)d_in[8];
    const float* br    = (const float*)d_in[9];
    float* out = (float*)d_out;

    char* ws = (char*)d_ws;
    size_t off = 0;
    auto alloc = [&](size_t bytes) -> char* {
        char* p = ws + off;
        off += (bytes + 255) & ~(size_t)255;
        return p;
    };
    f16* WqT = (f16*)alloc((size_t)65536 * 2);
    f16* WkT = (f16*)alloc((size_t)65536 * 2);
    f16* WvT = (f16*)alloc((size_t)65536 * 2);
    f16* WrT = (f16*)alloc((size_t)65536 * 2);
    f16* Qf  = (f16*)alloc((size_t)NB * S * 256 * 2);
    f16* Kf  = (f16*)alloc((size_t)NB * S * 256 * 2);
    f16* Hf  = (f16*)alloc((size_t)NB * S * 256 * 2);
    f16* VtF = (f16*)alloc((size_t)NB * S * 256 * 2);
    (void)ws_size; (void)in_sizes; (void)n_in; (void)out_size;

    // all four weight transposes in one launch
    wconv4_kernel<<<1024, 256, 0, stream>>>(Wq, Wk, Wv, Wr, WqT, WkT, WvT, WrT);

    // Q = query @ Wq + bq           (f16 row-major)
    proj_kernel<0, 0><<<512, 256, 0, stream>>>(query, nullptr, WqT, bq, Qf);
    // K = value @ Wk + bk (row-major) and V^T = (value @ Wv + bv)^T, fused
    kvproj_kernel<<<512, 512, 0, stream>>>(value, WkT, WvT, bk, bv, Kf, VtF);
    // Khat = cos(K @ Wr + br)       (f16 row-major)
    proj_kernel<1, 1><<<512, 256, 0, stream>>>(nullptr, Kf, WrT, br, Hf);

    // flash attention: KBLK=32, double-buffered K/V, one barrier per iter
    attn_kernel<<<256, 512, 0, stream>>>(Qf, Hf, VtF, out);
}

// Round 7
// 225.968 us; speedup vs baseline: 1.0375x; 1.0375x over previous
//
#include <hip/hip_runtime.h>
#include <hip/hip_bf16.h>

typedef _Float16 f16;
typedef _Float16 f16x8 __attribute__((ext_vector_type(8)));
typedef _Float16 f16x4 __attribute__((ext_vector_type(4)));
typedef float f32x4 __attribute__((ext_vector_type(4)));
typedef float f32x16 __attribute__((ext_vector_type(16)));

#define MFMA1632(a, b, c) __builtin_amdgcn_mfma_f32_16x16x32_f16(a, b, c, 0, 0, 0)
#define MFMA3216(a, b, c) __builtin_amdgcn_mfma_f32_32x32x16_f16(a, b, c, 0, 0, 0)

static constexpr int S  = 4096;
static constexpr int NB = 4;    // batches

// ---------------------------------------------------------------------------
// Weight convert + transpose, all four weights in one launch.
// ---------------------------------------------------------------------------
__global__ void wconv4_kernel(const float* __restrict__ W0, const float* __restrict__ W1,
                              const float* __restrict__ W2, const float* __restrict__ W3,
                              f16* __restrict__ T0, f16* __restrict__ T1,
                              f16* __restrict__ T2, f16* __restrict__ T3) {
    int j = blockIdx.x >> 8;
    int k = blockIdx.x & 255;
    int n = threadIdx.x;
    const float* W = (j == 0) ? W0 : (j == 1) ? W1 : (j == 2) ? W2 : W3;
    f16*         T = (j == 0) ? T0 : (j == 1) ? T1 : (j == 2) ? T2 : T3;
    T[n * 256 + k] = (f16)W[k * 256 + n];
}

// ---------------------------------------------------------------------------
// Projection GEMM (unchanged from round 6).
// ---------------------------------------------------------------------------
template <int ASRC, int OMODE>
__global__ __launch_bounds__(256) void proj_kernel(
    const float* __restrict__ Af, const f16* __restrict__ Ah,
    const f16* __restrict__ Wt, const float* __restrict__ bias,
    f16* __restrict__ O)
{
    int mbase = blockIdx.x * 32;
    int tid = threadIdx.x;
    int w = tid >> 6, l = tid & 63;
    int lr = l & 15, lg = l >> 4;
    int nbase = w * 64;

    f32x4 acc[2][4];
#pragma unroll
    for (int mf = 0; mf < 2; ++mf)
#pragma unroll
        for (int nf = 0; nf < 4; ++nf) acc[mf][nf] = f32x4{0.f, 0.f, 0.f, 0.f};

#pragma unroll
    for (int ks = 0; ks < 8; ++ks) {
        int kof = ks * 32 + lg * 8;
        f16x8 a[2], b[4];
#pragma unroll
        for (int mf = 0; mf < 2; ++mf) {
            int row = mbase + mf * 16 + lr;
            if (ASRC == 0) {
                const float4* p = (const float4*)(Af + row * 256 + kof);
                float4 x0 = p[0], x1 = p[1];
                f16x8 t;
                t[0] = (f16)x0.x; t[1] = (f16)x0.y; t[2] = (f16)x0.z; t[3] = (f16)x0.w;
                t[4] = (f16)x1.x; t[5] = (f16)x1.y; t[6] = (f16)x1.z; t[7] = (f16)x1.w;
                a[mf] = t;
            } else {
                a[mf] = *(const f16x8*)(Ah + row * 256 + kof);
            }
        }
#pragma unroll
        for (int nf = 0; nf < 4; ++nf) {
            int col = nbase + nf * 16 + lr;
            b[nf] = *(const f16x8*)(Wt + col * 256 + kof);
        }
#pragma unroll
        for (int mf = 0; mf < 2; ++mf)
#pragma unroll
            for (int nf = 0; nf < 4; ++nf)
                acc[mf][nf] = MFMA1632(a[mf], b[nf], acc[mf][nf]);
    }

#pragma unroll
    for (int mf = 0; mf < 2; ++mf) {
#pragma unroll
        for (int nf = 0; nf < 4; ++nf) {
            int col = nbase + nf * 16 + lr;
            float bv = bias[col];
#pragma unroll
            for (int r = 0; r < 4; ++r) {
                int row = mbase + mf * 16 + lg * 4 + r;
                float x = acc[mf][nf][r] + bv;
                if (OMODE == 1) x = cosf(x);
                O[row * 256 + col] = (f16)x;
            }
        }
    }
}

// ---------------------------------------------------------------------------
// Fused K+V projection (unchanged from round 6).
// ---------------------------------------------------------------------------
__global__ __launch_bounds__(512) void kvproj_kernel(
    const float* __restrict__ Af,
    const f16* __restrict__ WkT, const f16* __restrict__ WvT,
    const float* __restrict__ bk, const float* __restrict__ bv,
    f16* __restrict__ Kf, f16* __restrict__ VtF)
{
    int mbase = blockIdx.x * 32;
    int tid = threadIdx.x;
    int w = tid >> 6, l = tid & 63;
    int lr = l & 15, lg = l >> 4;
    int path = w >> 2;
    int nbase = (w & 3) * 64;
    const f16* Wt = path ? WvT : WkT;
    const float* bias = path ? bv : bk;

    f32x4 acc[2][4];
#pragma unroll
    for (int mf = 0; mf < 2; ++mf)
#pragma unroll
        for (int nf = 0; nf < 4; ++nf) acc[mf][nf] = f32x4{0.f, 0.f, 0.f, 0.f};

#pragma unroll
    for (int ks = 0; ks < 8; ++ks) {
        int kof = ks * 32 + lg * 8;
        f16x8 a[2], b[4];
#pragma unroll
        for (int mf = 0; mf < 2; ++mf) {
            int row = mbase + mf * 16 + lr;
            const float4* p = (const float4*)(Af + row * 256 + kof);
            float4 x0 = p[0], x1 = p[1];
            f16x8 t;
            t[0] = (f16)x0.x; t[1] = (f16)x0.y; t[2] = (f16)x0.z; t[3] = (f16)x0.w;
            t[4] = (f16)x1.x; t[5] = (f16)x1.y; t[6] = (f16)x1.z; t[7] = (f16)x1.w;
            a[mf] = t;
        }
#pragma unroll
        for (int nf = 0; nf < 4; ++nf) {
            int col = nbase + nf * 16 + lr;
            b[nf] = *(const f16x8*)(Wt + col * 256 + kof);
        }
#pragma unroll
        for (int mf = 0; mf < 2; ++mf)
#pragma unroll
            for (int nf = 0; nf < 4; ++nf)
                acc[mf][nf] = MFMA1632(a[mf], b[nf], acc[mf][nf]);
    }

#pragma unroll
    for (int mf = 0; mf < 2; ++mf) {
#pragma unroll
        for (int nf = 0; nf < 4; ++nf) {
            int col = nbase + nf * 16 + lr;
            float bv2 = bias[col];
            if (path == 0) {
#pragma unroll
                for (int r = 0; r < 4; ++r) {
                    int row = mbase + mf * 16 + lg * 4 + r;
                    Kf[row * 256 + col] = (f16)(acc[mf][nf][r] + bv2);
                }
            } else {
                int bi = mbase >> 12;
                int s  = (mbase & (S - 1)) + mf * 16 + lg * 4;
                f16x4 v;
#pragma unroll
                for (int r = 0; r < 4; ++r) v[r] = (f16)(acc[mf][nf][r] + bv2);
                *(f16x4*)(VtF + ((bi * 256 + col) * S + s)) = v;
            }
        }
    }
}

// ---------------------------------------------------------------------------
// Flash attention, 32x32 MFMAs, KBLK = 128, NT = 32, 2 barriers/iter.
//   8 waves: wave w -> qh = w>>2 (q-half, 32 rows), kg = w&3.
//   QK phase: wave (qh,kg) computes S^T[32k x 32q] = Khat[kg-slice] . Q[qh]
//     over 256 dims (16 MFMA_32x32x16). Lane owns ONE q (col = l&31),
//     16 keys (C/D rows) -> per-lane scalar softmax state.
//   P[64 q][128 k] through LDS.  PV phase: wave (qh, d-slice kg*64..+64):
//     O[32q x 64d] += P[q][128k] . V^T  (16 MFMA).  d-split -> no O merge.
//   Defer-max: block-shared max per q-row; steady state = compare + __any
//     + flag only; trigger path (rare) syncs max via LDS, rescales O.
//   K-hat single-buffered: reads end at B1, commit t+1 in B1-B2 window.
//   V committed same-iter in window (PV reads after B2).
// Grid: 256 blocks.  bid&7 -> XCD; batch b = (bid>>1)&3 pins to 2 XCDs.
// ---------------------------------------------------------------------------
__global__ __launch_bounds__(512, 2) void attn_kernel(
    const f16* __restrict__ Qf, const f16* __restrict__ Hf,
    const f16* __restrict__ Vt, float* __restrict__ Out)
{
    __shared__ f16 KhS[128][264];     // 67584 B  (row 528 B == 16 mod 128: spread)
    __shared__ f16 VtS[256][136];     // 69632 B
    __shared__ f16 PSh[64][136];      // 17408 B
    __shared__ float auxF[2][4][32];  // trigger max / epilogue lsum
    __shared__ float auxC[2][32];     // trigger corr / epilogue inv
    __shared__ int flagLds;

    int bid = blockIdx.x;
    int b   = (bid >> 1) & 3;
    int qi  = ((bid >> 3) << 1) | (bid & 1);
    int qbase = qi * 64;

    int tid = threadIdx.x;
    int w  = tid >> 6, l = tid & 63;
    int qh = w >> 2;            // q-half (0,1)
    int kg = w & 3;             // QK key-slice == PV d-slice
    int lm = l & 31;
    int h  = l >> 5;

    const f16* Hbase = Hf + (size_t)b * S * 256;
    const f16* Vbase = Vt + (size_t)b * 256 * S;

    // Q fragments: B-operand of S^T MFMA.  lane: q-col = qh*32+lm, dims h*8+..
    f16x8 qf[16];
    {
        const f16* qp = Qf + (size_t)(b * S + qbase + qh * 32 + lm) * 256 + h * 8;
#pragma unroll
        for (int s = 0; s < 16; ++s) qf[s] = *(const f16x8*)(qp + s * 16);
    }

    f32x16 oac0, oac1;
#pragma unroll
    for (int i = 0; i < 16; ++i) { oac0[i] = 0.f; oac1[i] = 0.f; }
    float mrun = -1e30f, lsum = 0.f;

    // prologue: stage K-hat tile 0
    {
        f16x8 rg[8];
#pragma unroll
        for (int i = 0; i < 8; ++i) {
            int c = i * 512 + tid;
            rg[i] = *(const f16x8*)(Hbase + (size_t)(c >> 5) * 256 + (c & 31) * 8);
        }
        if (tid == 0) flagLds = 0;
#pragma unroll
        for (int i = 0; i < 8; ++i) {
            int c = i * 512 + tid;
            *(f16x8*)&KhS[c >> 5][(c & 31) * 8] = rg[i];
        }
    }
    __syncthreads();

    const int NT = S / 128;     // 32 key-tiles
    for (int t = 0; t < NT; ++t) {
        int kt = t * 128;

        // 1. issue loads: V[t] (committed this iter), Khat[t+1]
        f16x8 rgV[8], rgK[8];
#pragma unroll
        for (int i = 0; i < 8; ++i) {
            int c = i * 512 + tid;
            rgV[i] = *(const f16x8*)(Vbase + (size_t)(c >> 4) * S + kt + (c & 15) * 8);
        }
        if (t + 1 < NT) {
#pragma unroll
            for (int i = 0; i < 8; ++i) {
                int c = i * 512 + tid;
                rgK[i] = *(const f16x8*)(Hbase + (size_t)(kt + 128 + (c >> 5)) * 256 + (c & 31) * 8);
            }
        }

        // 2. QK: S^T = Khat_slice . Q  (A = Khat[m=key], B = Q[n=q])
        f32x16 s0, s1;
#pragma unroll
        for (int i = 0; i < 16; ++i) { s0[i] = 0.f; s1[i] = 0.f; }
        __builtin_amdgcn_s_setprio(1);
#pragma unroll
        for (int s = 0; s < 16; s += 2) {
            f16x8 ka = *(const f16x8*)&KhS[kg * 32 + lm][s * 16 + h * 8];
            f16x8 kb = *(const f16x8*)&KhS[kg * 32 + lm][(s + 1) * 16 + h * 8];
            s0 = MFMA3216(ka, qf[s], s0);
            s1 = MFMA3216(kb, qf[s + 1], s1);
        }
        __builtin_amdgcn_s_setprio(0);
        f32x16 sc;
#pragma unroll
        for (int i = 0; i < 16; ++i) sc[i] = s0[i] + s1[i];

        // 3. defer-max trigger detect (block-shared max protocol)
        int need = 0;
#pragma unroll
        for (int i = 0; i < 16; ++i) need |= (sc[i] > mrun + 8.f) ? 1 : 0;
        if (__any(need)) { if (l == 0) flagLds = 1; }
        __syncthreads();                 // B1: Khat[t] reads done; flag combined

        if (flagLds) {                   // rare, block-uniform
            float mx = sc[0];
#pragma unroll
            for (int i = 1; i < 16; ++i) mx = fmaxf(mx, sc[i]);
            mx = fmaxf(mx, __shfl_xor(mx, 32));
            if (l < 32) auxF[qh][kg][lm] = mx;
            __syncthreads();
            float mnew = fmaxf(fmaxf(auxF[qh][0][lm], auxF[qh][1][lm]),
                               fmaxf(auxF[qh][2][lm], auxF[qh][3][lm]));
            mnew = fmaxf(mrun, mnew);
            float corr = __expf(mrun - mnew);
            lsum *= corr;
            if (kg == 0 && l < 32) auxC[qh][lm] = corr;
            mrun = mnew;
            if (tid == 0) flagLds = 0;
            __syncthreads();
            // rescale O accumulators (rows crow = (i&3)+8*(i>>2)+4h)
#pragma unroll
            for (int i = 0; i < 16; ++i) {
                float cr = auxC[qh][(i & 3) + 8 * (i >> 2) + 4 * h];
                oac0[i] *= cr;
                oac1[i] *= cr;
            }
        }

        // 4. exp + P write (row q = qh*32+lm, keys kg*32 + 8*b4 + 4h + j)
#pragma unroll
        for (int b4 = 0; b4 < 4; ++b4) {
            float p0 = __expf(sc[b4 * 4 + 0] - mrun);
            float p1 = __expf(sc[b4 * 4 + 1] - mrun);
            float p2 = __expf(sc[b4 * 4 + 2] - mrun);
            float p3 = __expf(sc[b4 * 4 + 3] - mrun);
            lsum += (p0 + p1) + (p2 + p3);
            f16x4 pv;
            pv[0] = (f16)p0; pv[1] = (f16)p1; pv[2] = (f16)p2; pv[3] = (f16)p3;
            *(f16x4*)&PSh[qh * 32 + lm][kg * 32 + 8 * b4 + 4 * h] = pv;
        }

        // 5. commit staged tiles (loads issued at step 1 -> latency hidden)
#pragma unroll
        for (int i = 0; i < 8; ++i) {
            int c = i * 512 + tid;
            *(f16x8*)&VtS[c >> 4][(c & 15) * 8] = rgV[i];
        }
        if (t + 1 < NT) {
#pragma unroll
            for (int i = 0; i < 8; ++i) {
                int c = i * 512 + tid;
                *(f16x8*)&KhS[c >> 5][(c & 31) * 8] = rgK[i];
            }
        }
        __syncthreads();                // B2: P, V[t], Khat[t+1] visible

        // 6. PV: O[32q x 64d] += P . V^T   (A = P[m=q], B = V^T[n=d])
        __builtin_amdgcn_s_setprio(1);
#pragma unroll
        for (int s = 0; s < 8; ++s) {
            f16x8 pa = *(const f16x8*)&PSh[qh * 32 + lm][s * 16 + h * 8];
            f16x8 v0 = *(const f16x8*)&VtS[kg * 64 + lm][s * 16 + h * 8];
            f16x8 v1 = *(const f16x8*)&VtS[kg * 64 + 32 + lm][s * 16 + h * 8];
            oac0 = MFMA3216(pa, v0, oac0);
            oac1 = MFMA3216(pa, v1, oac1);
        }
        __builtin_amdgcn_s_setprio(0);
    }

    // ---- epilogue: denominators across key-slices, then write (no O merge) ----
    lsum += __shfl_xor(lsum, 32);
    if (l < 32) auxF[qh][kg][lm] = lsum;
    __syncthreads();
    if (kg == 0 && l < 32) {
        float dsum = auxF[qh][0][lm] + auxF[qh][1][lm] +
                     auxF[qh][2][lm] + auxF[qh][3][lm];
        auxC[qh][lm] = 1.0f / dsum;
    }
    __syncthreads();

    float* Obase = Out + (size_t)(b * S + qbase + qh * 32) * 256 + kg * 64 + lm;
#pragma unroll
    for (int i = 0; i < 16; ++i) {
        int cr = (i & 3) + 8 * (i >> 2) + 4 * h;
        float inv = auxC[qh][cr];
        Obase[(size_t)cr * 256]      = oac0[i] * inv;
        Obase[(size_t)cr * 256 + 32] = oac1[i] * inv;
    }
}

// ---------------------------------------------------------------------------
extern "C" void kernel_launch(void* const* d_in, const int* in_sizes, int n_in,
                              void* d_out, int out_size, void* d_ws, size_t ws_size,
                              hipStream_t stream)
{
    const float* query = (const float*)d_in[0];
    const float* value = (const float*)d_in[1];
    const float* Wq    = (const float*)d_in[2];
    const float* bq    = (const float*)d_in[3];
    const float* Wk    = (const float*)d_in[4];
    const float* bk    = (const float*)d_in[5];
    const float* Wv    = (const float*)d_in[6];
    const float* bv    = (const float*)d_in[7];
    const float* Wr    = (const float*)d_in[8];
    const float* br    = (const float*)d_in[9];
    float* out = (float*)d_out;

    char* ws = (char*)d_ws;
    size_t off = 0;
    auto alloc = [&](size_t bytes) -> char* {
        char* p = ws + off;
        off += (bytes + 255) & ~(size_t)255;
        return p;
    };
    f16* WqT = (f16*)alloc((size_t)65536 * 2);
    f16* WkT = (f16*)alloc((size_t)65536 * 2);
    f16* WvT = (f16*)alloc((size_t)65536 * 2);
    f16* WrT = (f16*)alloc((size_t)65536 * 2);
    f16* Qf  = (f16*)alloc((size_t)NB * S * 256 * 2);
    f16* Kf  = (f16*)alloc((size_t)NB * S * 256 * 2);
    f16* Hf  = (f16*)alloc((size_t)NB * S * 256 * 2);
    f16* VtF = (f16*)alloc((size_t)NB * S * 256 * 2);
    (void)ws_size; (void)in_sizes; (void)n_in; (void)out_size;

    wconv4_kernel<<<1024, 256, 0, stream>>>(Wq, Wk, Wv, Wr, WqT, WkT, WvT, WrT);

    // Q = query @ Wq + bq           (f16 row-major)
    proj_kernel<0, 0><<<512, 256, 0, stream>>>(query, nullptr, WqT, bq, Qf);
    // K = value @ Wk + bk (row-major) and V^T = (value @ Wv + bv)^T, fused
    kvproj_kernel<<<512, 512, 0, stream>>>(value, WkT, WvT, bk, bv, Kf, VtF);
    // Khat = cos(K @ Wr + br)       (f16 row-major)
    proj_kernel<1, 1><<<512, 256, 0, stream>>>(nullptr, Kf, WrT, br, Hf);

    // flash attention: 32x32 MFMAs, KBLK=128, d-split PV, 2 barriers/iter
    attn_kernel<<<256, 512, 0, stream>>>(Qf, Hf, VtF, out);
}

// Round 8
// 213.605 us; speedup vs baseline: 1.0975x; 1.0579x over previous
//
#include <hip/hip_runtime.h>
#include <hip/hip_bf16.h>

typedef _Float16 f16;
typedef _Float16 f16x8 __attribute__((ext_vector_type(8)));
typedef _Float16 f16x4 __attribute__((ext_vector_type(4)));
typedef float f32x4 __attribute__((ext_vector_type(4)));
typedef float f32x16 __attribute__((ext_vector_type(16)));

#define MFMA1632(a, b, c) __builtin_amdgcn_mfma_f32_16x16x32_f16(a, b, c, 0, 0, 0)
#define MFMA3216(a, b, c) __builtin_amdgcn_mfma_f32_32x32x16_f16(a, b, c, 0, 0, 0)

// async global->LDS, 16B per lane; LDS dest = wave-uniform base + lane*16
#define GLL16(g, l)                                                        \
    __builtin_amdgcn_global_load_lds(                                      \
        (const __attribute__((address_space(1))) void*)(g),                \
        (__attribute__((address_space(3))) void*)(l), 16, 0, 0)

static constexpr int S  = 4096;
static constexpr int NB = 4;    // batches

// ---------------------------------------------------------------------------
// Weight convert + transpose, all four weights in one launch.
// ---------------------------------------------------------------------------
__global__ void wconv4_kernel(const float* __restrict__ W0, const float* __restrict__ W1,
                              const float* __restrict__ W2, const float* __restrict__ W3,
                              f16* __restrict__ T0, f16* __restrict__ T1,
                              f16* __restrict__ T2, f16* __restrict__ T3) {
    int j = blockIdx.x >> 8;
    int k = blockIdx.x & 255;
    int n = threadIdx.x;
    const float* W = (j == 0) ? W0 : (j == 1) ? W1 : (j == 2) ? W2 : W3;
    f16*         T = (j == 0) ? T0 : (j == 1) ? T1 : (j == 2) ? T2 : T3;
    T[n * 256 + k] = (f16)W[k * 256 + n];
}

// ---------------------------------------------------------------------------
// Projection GEMM (unchanged, proven).
// ---------------------------------------------------------------------------
template <int ASRC, int OMODE>
__global__ __launch_bounds__(256) void proj_kernel(
    const float* __restrict__ Af, const f16* __restrict__ Ah,
    const f16* __restrict__ Wt, const float* __restrict__ bias,
    f16* __restrict__ O)
{
    int mbase = blockIdx.x * 32;
    int tid = threadIdx.x;
    int w = tid >> 6, l = tid & 63;
    int lr = l & 15, lg = l >> 4;
    int nbase = w * 64;

    f32x4 acc[2][4];
#pragma unroll
    for (int mf = 0; mf < 2; ++mf)
#pragma unroll
        for (int nf = 0; nf < 4; ++nf) acc[mf][nf] = f32x4{0.f, 0.f, 0.f, 0.f};

#pragma unroll
    for (int ks = 0; ks < 8; ++ks) {
        int kof = ks * 32 + lg * 8;
        f16x8 a[2], b[4];
#pragma unroll
        for (int mf = 0; mf < 2; ++mf) {
            int row = mbase + mf * 16 + lr;
            if (ASRC == 0) {
                const float4* p = (const float4*)(Af + row * 256 + kof);
                float4 x0 = p[0], x1 = p[1];
                f16x8 t;
                t[0] = (f16)x0.x; t[1] = (f16)x0.y; t[2] = (f16)x0.z; t[3] = (f16)x0.w;
                t[4] = (f16)x1.x; t[5] = (f16)x1.y; t[6] = (f16)x1.z; t[7] = (f16)x1.w;
                a[mf] = t;
            } else {
                a[mf] = *(const f16x8*)(Ah + row * 256 + kof);
            }
        }
#pragma unroll
        for (int nf = 0; nf < 4; ++nf) {
            int col = nbase + nf * 16 + lr;
            b[nf] = *(const f16x8*)(Wt + col * 256 + kof);
        }
#pragma unroll
        for (int mf = 0; mf < 2; ++mf)
#pragma unroll
            for (int nf = 0; nf < 4; ++nf)
                acc[mf][nf] = MFMA1632(a[mf], b[nf], acc[mf][nf]);
    }

#pragma unroll
    for (int mf = 0; mf < 2; ++mf) {
#pragma unroll
        for (int nf = 0; nf < 4; ++nf) {
            int col = nbase + nf * 16 + lr;
            float bv = bias[col];
#pragma unroll
            for (int r = 0; r < 4; ++r) {
                int row = mbase + mf * 16 + lg * 4 + r;
                float x = acc[mf][nf][r] + bv;
                if (OMODE == 1) x = cosf(x);
                O[row * 256 + col] = (f16)x;
            }
        }
    }
}

// ---------------------------------------------------------------------------
// Fused K+V projection (unchanged, proven).
// ---------------------------------------------------------------------------
__global__ __launch_bounds__(512) void kvproj_kernel(
    const float* __restrict__ Af,
    const f16* __restrict__ WkT, const f16* __restrict__ WvT,
    const float* __restrict__ bk, const float* __restrict__ bv,
    f16* __restrict__ Kf, f16* __restrict__ VtF)
{
    int mbase = blockIdx.x * 32;
    int tid = threadIdx.x;
    int w = tid >> 6, l = tid & 63;
    int lr = l & 15, lg = l >> 4;
    int path = w >> 2;
    int nbase = (w & 3) * 64;
    const f16* Wt = path ? WvT : WkT;
    const float* bias = path ? bv : bk;

    f32x4 acc[2][4];
#pragma unroll
    for (int mf = 0; mf < 2; ++mf)
#pragma unroll
        for (int nf = 0; nf < 4; ++nf) acc[mf][nf] = f32x4{0.f, 0.f, 0.f, 0.f};

#pragma unroll
    for (int ks = 0; ks < 8; ++ks) {
        int kof = ks * 32 + lg * 8;
        f16x8 a[2], b[4];
#pragma unroll
        for (int mf = 0; mf < 2; ++mf) {
            int row = mbase + mf * 16 + lr;
            const float4* p = (const float4*)(Af + row * 256 + kof);
            float4 x0 = p[0], x1 = p[1];
            f16x8 t;
            t[0] = (f16)x0.x; t[1] = (f16)x0.y; t[2] = (f16)x0.z; t[3] = (f16)x0.w;
            t[4] = (f16)x1.x; t[5] = (f16)x1.y; t[6] = (f16)x1.z; t[7] = (f16)x1.w;
            a[mf] = t;
        }
#pragma unroll
        for (int nf = 0; nf < 4; ++nf) {
            int col = nbase + nf * 16 + lr;
            b[nf] = *(const f16x8*)(Wt + col * 256 + kof);
        }
#pragma unroll
        for (int mf = 0; mf < 2; ++mf)
#pragma unroll
            for (int nf = 0; nf < 4; ++nf)
                acc[mf][nf] = MFMA1632(a[mf], b[nf], acc[mf][nf]);
    }

#pragma unroll
    for (int mf = 0; mf < 2; ++mf) {
#pragma unroll
        for (int nf = 0; nf < 4; ++nf) {
            int col = nbase + nf * 16 + lr;
            float bv2 = bias[col];
            if (path == 0) {
#pragma unroll
                for (int r = 0; r < 4; ++r) {
                    int row = mbase + mf * 16 + lg * 4 + r;
                    Kf[row * 256 + col] = (f16)(acc[mf][nf][r] + bv2);
                }
            } else {
                int bi = mbase >> 12;
                int s  = (mbase & (S - 1)) + mf * 16 + lg * 4;
                f16x4 v;
#pragma unroll
                for (int r = 0; r < 4; ++r) v[r] = (f16)(acc[mf][nf][r] + bv2);
                *(f16x4*)(VtF + ((bi * 256 + col) * S + s)) = v;
            }
        }
    }
}

// ---------------------------------------------------------------------------
// Flash attention, 32x32 MFMAs, KBLK = 128, NT = 32, 2 barriers/iter.
//   QK: wave (qh = w>>2, kg = w&3) computes S^T[32k x 32q]; lane owns one
//     q-col -> per-lane scalar softmax (defer-max flag protocol, uniform mrun).
//   K-hat: global_load_lds, DOUBLE-buffered [2][128][256] f16, source
//     pre-swizzled chunk^=(row&7), reads XOR the same way (rule #21).
//   P[64][128] f16 in LDS, same swizzle.
//   PV: wave w owns d-slice w*32..+32; V^T fragments read DIRECT from global
//     (each V row read by exactly one wave -> no duplication), rgV issued at
//     iteration top (~2000 cy cover). O covers both q-halves -> no O merge.
// Grid: 256 blocks.  bid&7 -> XCD; batch b = (bid>>1)&3 pins to 2 XCDs.
// ---------------------------------------------------------------------------
__global__ __launch_bounds__(512, 1) void attn_kernel(
    const f16* __restrict__ Qf, const f16* __restrict__ Hf,
    const f16* __restrict__ Vt, float* __restrict__ Out)
{
    __shared__ f16 KhS[2][128 * 256];   // 131072 B, chunk-swizzled rows
    __shared__ f16 PSh[64 * 128];       // 16384 B, chunk-swizzled rows
    __shared__ float auxF[2][4][32];    // per-(qh,kg) row max / lsum partials
    __shared__ float auxT[2][32];       // trigger corr
    __shared__ float auxC[2][32];       // epilogue 1/denominator
    __shared__ int flagLds;

    int bid = blockIdx.x;
    int b   = (bid >> 1) & 3;
    int qi  = ((bid >> 3) << 1) | (bid & 1);
    int qbase = qi * 64;

    int tid = threadIdx.x;
    int w  = tid >> 6, l = tid & 63;
    int qh = w >> 2;            // QK q-half
    int kg = w & 3;             // QK key-slice; (also PV reuses w as d-slice)
    int lm = l & 31;
    int h  = l >> 5;
    int sw = lm & 7;            // XOR-swizzle key (row&7 for all our tiles)

    const f16* Hbase = Hf + (size_t)b * S * 256;
    const f16* Vbase = Vt + (size_t)b * 256 * S;

    // Q fragments (B-operand of S^T): q-col = qbase + qh*32 + lm
    f16x8 qf[16];
    {
        const f16* qp = Qf + (size_t)(b * S + qbase + qh * 32 + lm) * 256 + h * 8;
#pragma unroll
        for (int s = 0; s < 16; ++s) qf[s] = *(const f16x8*)(qp + s * 16);
    }

    f32x16 oac0, oac1;
#pragma unroll
    for (int i = 0; i < 16; ++i) { oac0[i] = 0.f; oac1[i] = 0.f; }
    float mrun = -1e30f, lsum = 0.f;

    // prologue: async-stage K-hat tile 0 into buffer 0 (source pre-swizzled)
    if (tid == 0) flagLds = 0;
#pragma unroll
    for (int i = 0; i < 8; ++i) {
        int c = i * 512 + tid;
        int row = c >> 5, ch = c & 31;
        GLL16(Hbase + (size_t)row * 256 + ((ch ^ (row & 7)) * 8),
              &KhS[0][(size_t)(i * 512 + w * 64) * 8]);
    }
    __syncthreads();   // compiler drains vmcnt before barrier -> tile 0 landed

    const int NT = S / 128;     // 32 key-tiles
    for (int t = 0; t < NT; ++t) {
        int cur = t & 1;
        int kt = t * 128;

        // 1. V fragments for PV (this wave's 32 d-rows) -- direct global,
        //    issued at top so QK+softmax covers the latency
        f16x8 rgV[8];
        {
            const f16* vp = Vbase + (size_t)(w * 32 + lm) * S + kt + h * 8;
#pragma unroll
            for (int s = 0; s < 8; ++s) rgV[s] = *(const f16x8*)(vp + s * 16);
        }

        // 2. async-stage K-hat tile t+1 into the other buffer
        if (t + 1 < NT) {
#pragma unroll
            for (int i = 0; i < 8; ++i) {
                int c = i * 512 + tid;
                int row = c >> 5, ch = c & 31;
                GLL16(Hbase + (size_t)(kt + 128 + row) * 256 + ((ch ^ (row & 7)) * 8),
                      &KhS[cur ^ 1][(size_t)(i * 512 + w * 64) * 8]);
            }
        }

        // 3. QK: S^T = Khat_slice . Q   (A rows = keys, B cols = q)
        f32x16 s0, s1;
#pragma unroll
        for (int i = 0; i < 16; ++i) { s0[i] = 0.f; s1[i] = 0.f; }
        {
            const f16* kb = &KhS[cur][(size_t)(kg * 32 + lm) * 256];
            __builtin_amdgcn_s_setprio(1);
#pragma unroll
            for (int s = 0; s < 16; s += 2) {
                f16x8 ka0 = *(const f16x8*)(kb + ((2 * s + h) ^ sw) * 8);
                f16x8 ka1 = *(const f16x8*)(kb + ((2 * s + 2 + h) ^ sw) * 8);
                s0 = MFMA3216(ka0, qf[s], s0);
                s1 = MFMA3216(ka1, qf[s + 1], s1);
            }
            __builtin_amdgcn_s_setprio(0);
        }
        f32x16 sc;
#pragma unroll
        for (int i = 0; i < 16; ++i) sc[i] = s0[i] + s1[i];

        // 4. defer-max trigger detect (block-uniform flag protocol)
        int need = 0;
#pragma unroll
        for (int i = 0; i < 16; ++i) need |= (sc[i] > mrun + 8.f) ? 1 : 0;
        if (__any(need)) { if (l == 0) flagLds = 1; }
        __syncthreads();                 // B1: flag combined; QK reads done

        if (flagLds) {                   // rare, block-uniform
            float mx = sc[0];
#pragma unroll
            for (int i = 1; i < 16; ++i) mx = fmaxf(mx, sc[i]);
            mx = fmaxf(mx, __shfl_xor(mx, 32));
            if (l < 32) auxF[qh][kg][lm] = mx;
            __syncthreads();
            float mnew = fmaxf(fmaxf(auxF[qh][0][lm], auxF[qh][1][lm]),
                               fmaxf(auxF[qh][2][lm], auxF[qh][3][lm]));
            mnew = fmaxf(mrun, mnew);
            float corr = __expf(mrun - mnew);
            lsum *= corr;
            if (kg == 0 && l < 32) auxT[qh][lm] = corr;
            mrun = mnew;
            if (tid == 0) flagLds = 0;
            __syncthreads();
            // rescale O accumulators (both q-halves)
#pragma unroll
            for (int i = 0; i < 16; ++i) {
                int cr = (i & 3) + 8 * (i >> 2) + 4 * h;
                oac0[i] *= auxT[0][cr];
                oac1[i] *= auxT[1][cr];
            }
        }

        // 5. exp + P write (row q = qh*32+lm; key chunk (4kg+b4), swizzled)
        {
            f16* pbase = &PSh[(size_t)(qh * 32 + lm) * 128];
#pragma unroll
            for (int b4 = 0; b4 < 4; ++b4) {
                float p0 = __expf(sc[b4 * 4 + 0] - mrun);
                float p1 = __expf(sc[b4 * 4 + 1] - mrun);
                float p2 = __expf(sc[b4 * 4 + 2] - mrun);
                float p3 = __expf(sc[b4 * 4 + 3] - mrun);
                lsum += (p0 + p1) + (p2 + p3);
                f16x4 pv;
                pv[0] = (f16)p0; pv[1] = (f16)p1; pv[2] = (f16)p2; pv[3] = (f16)p3;
                *(f16x4*)(pbase + (((4 * kg + b4) ^ sw) * 8 + 4 * h)) = pv;
            }
        }

        __syncthreads();                 // B2: P visible; gll tile t+1 landed

        // 6. PV: O[64 q x 32 d] += P . V^T   (A = P rows=q, B = rgV cols=d)
        {
            const f16* pb0 = &PSh[(size_t)lm * 128];
            const f16* pb1 = &PSh[(size_t)(32 + lm) * 128];
            __builtin_amdgcn_s_setprio(1);
#pragma unroll
            for (int s = 0; s < 8; ++s) {
                f16x8 pa0 = *(const f16x8*)(pb0 + ((2 * s + h) ^ sw) * 8);
                f16x8 pa1 = *(const f16x8*)(pb1 + ((2 * s + h) ^ sw) * 8);
                oac0 = MFMA3216(pa0, rgV[s], oac0);
                oac1 = MFMA3216(pa1, rgV[s], oac1);
            }
            __builtin_amdgcn_s_setprio(0);
        }
    }

    // ---- epilogue: denominators (kg x h partials), then write; no O merge ----
    lsum += __shfl_xor(lsum, 32);
    if (l < 32) auxF[qh][kg][lm] = lsum;
    __syncthreads();
    if (kg == 0 && l < 32) {
        float dsum = auxF[qh][0][lm] + auxF[qh][1][lm] +
                     auxF[qh][2][lm] + auxF[qh][3][lm];
        auxC[qh][lm] = 1.0f / dsum;
    }
    __syncthreads();

    float* Ob = Out + (size_t)(b * S + qbase) * 256 + w * 32 + lm;
#pragma unroll
    for (int i = 0; i < 16; ++i) {
        int cr = (i & 3) + 8 * (i >> 2) + 4 * h;
        Ob[(size_t)cr * 256]        = oac0[i] * auxC[0][cr];
        Ob[(size_t)(32 + cr) * 256] = oac1[i] * auxC[1][cr];
    }
}

// ---------------------------------------------------------------------------
extern "C" void kernel_launch(void* const* d_in, const int* in_sizes, int n_in,
                              void* d_out, int out_size, void* d_ws, size_t ws_size,
                              hipStream_t stream)
{
    const float* query = (const float*)d_in[0];
    const float* value = (const float*)d_in[1];
    const float* Wq    = (const float*)d_in[2];
    const float* bq    = (const float*)d_in[3];
    const float* Wk    = (const float*)d_in[4];
    const float* bk    = (const float*)d_in[5];
    const float* Wv    = (const float*)d_in[6];
    const float* bv    = (const float*)d_in[7];
    const float* Wr    = (const float*)d_in[8];
    const float* br    = (const float*)d_in[9];
    float* out = (float*)d_out;

    char* ws = (char*)d_ws;
    size_t off = 0;
    auto alloc = [&](size_t bytes) -> char* {
        char* p = ws + off;
        off += (bytes + 255) & ~(size_t)255;
        return p;
    };
    f16* WqT = (f16*)alloc((size_t)65536 * 2);
    f16* WkT = (f16*)alloc((size_t)65536 * 2);
    f16* WvT = (f16*)alloc((size_t)65536 * 2);
    f16* WrT = (f16*)alloc((size_t)65536 * 2);
    f16* Qf  = (f16*)alloc((size_t)NB * S * 256 * 2);
    f16* Kf  = (f16*)alloc((size_t)NB * S * 256 * 2);
    f16* Hf  = (f16*)alloc((size_t)NB * S * 256 * 2);
    f16* VtF = (f16*)alloc((size_t)NB * S * 256 * 2);
    (void)ws_size; (void)in_sizes; (void)n_in; (void)out_size;

    wconv4_kernel<<<1024, 256, 0, stream>>>(Wq, Wk, Wv, Wr, WqT, WkT, WvT, WrT);

    // Q = query @ Wq + bq           (f16 row-major)
    proj_kernel<0, 0><<<512, 256, 0, stream>>>(query, nullptr, WqT, bq, Qf);
    // K = value @ Wk + bk (row-major) and V^T = (value @ Wv + bv)^T, fused
    kvproj_kernel<<<512, 512, 0, stream>>>(value, WkT, WvT, bk, bv, Kf, VtF);
    // Khat = cos(K @ Wr + br)       (f16 row-major)
    proj_kernel<1, 1><<<512, 256, 0, stream>>>(nullptr, Kf, WrT, br, Hf);

    // flash attention: 32x32 MFMAs, gll-staged K-hat, direct-global V
    attn_kernel<<<256, 512, 0, stream>>>(Qf, Hf, VtF, out);
}

// Round 9
// 173.479 us; speedup vs baseline: 1.3514x; 1.2313x over previous
//
#include <hip/hip_runtime.h>
#include <hip/hip_bf16.h>

typedef _Float16 f16;
typedef _Float16 f16x8 __attribute__((ext_vector_type(8)));
typedef _Float16 f16x4 __attribute__((ext_vector_type(4)));
typedef float f32x4 __attribute__((ext_vector_type(4)));
typedef float f32x16 __attribute__((ext_vector_type(16)));

#define MFMA1632(a, b, c) __builtin_amdgcn_mfma_f32_16x16x32_f16(a, b, c, 0, 0, 0)
#define MFMA3216(a, b, c) __builtin_amdgcn_mfma_f32_32x32x16_f16(a, b, c, 0, 0, 0)

// async global->LDS, 16B per lane; LDS dest = wave-uniform base + lane*16
#define GLL16(g, l)                                                        \
    __builtin_amdgcn_global_load_lds(                                      \
        (const __attribute__((address_space(1))) void*)(g),                \
        (__attribute__((address_space(3))) void*)(l), 16, 0, 0)

static constexpr int S  = 4096;
static constexpr int NB = 4;    // batches

// ---------------------------------------------------------------------------
// Weight convert + transpose, all four weights in one launch.
// ---------------------------------------------------------------------------
__global__ void wconv4_kernel(const float* __restrict__ W0, const float* __restrict__ W1,
                              const float* __restrict__ W2, const float* __restrict__ W3,
                              f16* __restrict__ T0, f16* __restrict__ T1,
                              f16* __restrict__ T2, f16* __restrict__ T3) {
    int j = blockIdx.x >> 8;
    int k = blockIdx.x & 255;
    int n = threadIdx.x;
    const float* W = (j == 0) ? W0 : (j == 1) ? W1 : (j == 2) ? W2 : W3;
    f16*         T = (j == 0) ? T0 : (j == 1) ? T1 : (j == 2) ? T2 : T3;
    T[n * 256 + k] = (f16)W[k * 256 + n];
}

// ---------------------------------------------------------------------------
// Projection GEMM (unchanged, proven).
// ---------------------------------------------------------------------------
template <int ASRC, int OMODE>
__global__ __launch_bounds__(256) void proj_kernel(
    const float* __restrict__ Af, const f16* __restrict__ Ah,
    const f16* __restrict__ Wt, const float* __restrict__ bias,
    f16* __restrict__ O)
{
    int mbase = blockIdx.x * 32;
    int tid = threadIdx.x;
    int w = tid >> 6, l = tid & 63;
    int lr = l & 15, lg = l >> 4;
    int nbase = w * 64;

    f32x4 acc[2][4];
#pragma unroll
    for (int mf = 0; mf < 2; ++mf)
#pragma unroll
        for (int nf = 0; nf < 4; ++nf) acc[mf][nf] = f32x4{0.f, 0.f, 0.f, 0.f};

#pragma unroll
    for (int ks = 0; ks < 8; ++ks) {
        int kof = ks * 32 + lg * 8;
        f16x8 a[2], b[4];
#pragma unroll
        for (int mf = 0; mf < 2; ++mf) {
            int row = mbase + mf * 16 + lr;
            if (ASRC == 0) {
                const float4* p = (const float4*)(Af + row * 256 + kof);
                float4 x0 = p[0], x1 = p[1];
                f16x8 t;
                t[0] = (f16)x0.x; t[1] = (f16)x0.y; t[2] = (f16)x0.z; t[3] = (f16)x0.w;
                t[4] = (f16)x1.x; t[5] = (f16)x1.y; t[6] = (f16)x1.z; t[7] = (f16)x1.w;
                a[mf] = t;
            } else {
                a[mf] = *(const f16x8*)(Ah + row * 256 + kof);
            }
        }
#pragma unroll
        for (int nf = 0; nf < 4; ++nf) {
            int col = nbase + nf * 16 + lr;
            b[nf] = *(const f16x8*)(Wt + col * 256 + kof);
        }
#pragma unroll
        for (int mf = 0; mf < 2; ++mf)
#pragma unroll
            for (int nf = 0; nf < 4; ++nf)
                acc[mf][nf] = MFMA1632(a[mf], b[nf], acc[mf][nf]);
    }

#pragma unroll
    for (int mf = 0; mf < 2; ++mf) {
#pragma unroll
        for (int nf = 0; nf < 4; ++nf) {
            int col = nbase + nf * 16 + lr;
            float bv = bias[col];
#pragma unroll
            for (int r = 0; r < 4; ++r) {
                int row = mbase + mf * 16 + lg * 4 + r;
                float x = acc[mf][nf][r] + bv;
                if (OMODE == 1) x = cosf(x);
                O[row * 256 + col] = (f16)x;
            }
        }
    }
}

// ---------------------------------------------------------------------------
// Fused K+V projection (unchanged, proven).
// ---------------------------------------------------------------------------
__global__ __launch_bounds__(512) void kvproj_kernel(
    const float* __restrict__ Af,
    const f16* __restrict__ WkT, const f16* __restrict__ WvT,
    const float* __restrict__ bk, const float* __restrict__ bv,
    f16* __restrict__ Kf, f16* __restrict__ VtF)
{
    int mbase = blockIdx.x * 32;
    int tid = threadIdx.x;
    int w = tid >> 6, l = tid & 63;
    int lr = l & 15, lg = l >> 4;
    int path = w >> 2;
    int nbase = (w & 3) * 64;
    const f16* Wt = path ? WvT : WkT;
    const float* bias = path ? bv : bk;

    f32x4 acc[2][4];
#pragma unroll
    for (int mf = 0; mf < 2; ++mf)
#pragma unroll
        for (int nf = 0; nf < 4; ++nf) acc[mf][nf] = f32x4{0.f, 0.f, 0.f, 0.f};

#pragma unroll
    for (int ks = 0; ks < 8; ++ks) {
        int kof = ks * 32 + lg * 8;
        f16x8 a[2], b[4];
#pragma unroll
        for (int mf = 0; mf < 2; ++mf) {
            int row = mbase + mf * 16 + lr;
            const float4* p = (const float4*)(Af + row * 256 + kof);
            float4 x0 = p[0], x1 = p[1];
            f16x8 t;
            t[0] = (f16)x0.x; t[1] = (f16)x0.y; t[2] = (f16)x0.z; t[3] = (f16)x0.w;
            t[4] = (f16)x1.x; t[5] = (f16)x1.y; t[6] = (f16)x1.z; t[7] = (f16)x1.w;
            a[mf] = t;
        }
#pragma unroll
        for (int nf = 0; nf < 4; ++nf) {
            int col = nbase + nf * 16 + lr;
            b[nf] = *(const f16x8*)(Wt + col * 256 + kof);
        }
#pragma unroll
        for (int mf = 0; mf < 2; ++mf)
#pragma unroll
            for (int nf = 0; nf < 4; ++nf)
                acc[mf][nf] = MFMA1632(a[mf], b[nf], acc[mf][nf]);
    }

#pragma unroll
    for (int mf = 0; mf < 2; ++mf) {
#pragma unroll
        for (int nf = 0; nf < 4; ++nf) {
            int col = nbase + nf * 16 + lr;
            float bv2 = bias[col];
            if (path == 0) {
#pragma unroll
                for (int r = 0; r < 4; ++r) {
                    int row = mbase + mf * 16 + lg * 4 + r;
                    Kf[row * 256 + col] = (f16)(acc[mf][nf][r] + bv2);
                }
            } else {
                int bi = mbase >> 12;
                int s  = (mbase & (S - 1)) + mf * 16 + lg * 4;
                f16x4 v;
#pragma unroll
                for (int r = 0; r < 4; ++r) v[r] = (f16)(acc[mf][nf][r] + bv2);
                *(f16x4*)(VtF + ((bi * 256 + col) * S + s)) = v;
            }
        }
    }
}

// ---------------------------------------------------------------------------
// Flash attention, 32x32 MFMAs, KBLK=128, NT=32, 2 barriers/iter.
//   ALL staging via global_load_lds (zero staging VGPRs).
//   K-hat [128][256] f16 single-buffered, swizzle key row&31 (full width):
//     gll issued after B1 (reads of tile t done), drained at B2.
//   V^T stored PAIRED: physical row pr=d>>1 holds d and d+1 (256 f16 = 32
//     chunks) -> full 5-bit swizzle key. Wave w reads ONLY d-rows w*32..+32,
//     and glls exactly that slice post-PV -> no race, 1-iter latency cover.
//   P [64 q][128 k] also paired (pr=q>>1), conflict-free writes and reads.
//   QK: wave (qh=w>>2, kg=w&3): S^T[32k x 32q], lane owns one q-col ->
//     per-lane scalar softmax, block-uniform defer-max flag protocol.
//   PV: wave w owns d-slice w*32..+32 over BOTH q-halves -> no O merge.
// Grid: 256 blocks.  bid&7 -> XCD; batch b = (bid>>1)&3 pins to 2 XCDs.
// ---------------------------------------------------------------------------
__global__ __launch_bounds__(512, 2) void attn_kernel(
    const f16* __restrict__ Qf, const f16* __restrict__ Hf,
    const f16* __restrict__ Vt, float* __restrict__ Out)
{
    __shared__ f16 KhS[128 * 256];      // 64 KB  (chunk c holds logical c^(row&31))
    __shared__ f16 VtS2[128 * 256];     // 64 KB  paired rows, swizzled
    __shared__ f16 PSh2[32 * 256];      // 16 KB  paired rows, swizzled
    __shared__ float auxF[2][4][32];    // per-(qh,kg) row max / lsum partials
    __shared__ float auxT[2][32];       // trigger corr
    __shared__ float auxC[2][32];       // epilogue 1/denominator
    __shared__ int flagLds;

    int bid = blockIdx.x;
    int b   = (bid >> 1) & 3;
    int qi  = ((bid >> 3) << 1) | (bid & 1);
    int qbase = qi * 64;

    int tid = threadIdx.x;
    int w  = tid >> 6, l = tid & 63;
    int qh = w >> 2;            // QK q-half
    int kg = w & 3;             // QK key-slice
    int lm = l & 31;
    int h  = l >> 5;

    const f16* Hbase = Hf + (size_t)b * S * 256;
    const f16* Vbase = Vt + (size_t)b * 256 * S;

    // Q fragments (B-operand of S^T): q-col = qbase + qh*32 + lm  (64 VGPR)
    f16x8 qf[16];
    {
        const f16* qp = Qf + (size_t)(b * S + qbase + qh * 32 + lm) * 256 + h * 8;
#pragma unroll
        for (int s = 0; s < 16; ++s) qf[s] = *(const f16x8*)(qp + s * 16);
    }

    f32x16 oac0, oac1;
#pragma unroll
    for (int i = 0; i < 16; ++i) { oac0[i] = 0.f; oac1[i] = 0.f; }
    float mrun = -1e30f, lsum = 0.f;

    if (tid == 0) flagLds = 0;

    // ---- prologue: gll-stage K-hat[0] (all threads) and V[0] (wave-sliced)
#pragma unroll
    for (int i = 0; i < 8; ++i) {
        int c = i * 512 + tid;
        int row = c >> 5, ch = c & 31;
        GLL16(Hbase + (size_t)row * 256 + ((ch ^ (row & 31)) * 8),
              KhS + (size_t)(i * 4096 + w * 512));
    }
#pragma unroll
    for (int i = 0; i < 8; ++i) {
        int j   = i * 64 + l;
        int prv = j >> 5, pc = j & 31;
        int kap = (w * 16 + prv) & 31;
        int lc  = pc ^ kap;
        int d   = w * 32 + prv * 2 + (lc >> 4);
        GLL16(Vbase + (size_t)d * S + ((lc & 15) * 8),
              VtS2 + (size_t)(w * 4096 + i * 512));
    }
    __syncthreads();    // drains vmcnt -> both tiles landed

    const int NT = S / 128;     // 32 key-tiles
    for (int t = 0; t < NT; ++t) {
        int kt = t * 128;

        // ---- QK: S^T = Khat_slice . Q  (A rows = keys, B cols = q) ----
        f32x16 s0, s1;
#pragma unroll
        for (int i = 0; i < 16; ++i) { s0[i] = 0.f; s1[i] = 0.f; }
        {
            const f16* kb = KhS + (size_t)(kg * 32 + lm) * 256;
            __builtin_amdgcn_s_setprio(1);
#pragma unroll
            for (int s = 0; s < 16; s += 2) {
                f16x8 ka0 = *(const f16x8*)(kb + ((2 * s + h) ^ lm) * 8);
                f16x8 ka1 = *(const f16x8*)(kb + ((2 * s + 2 + h) ^ lm) * 8);
                s0 = MFMA3216(ka0, qf[s], s0);
                s1 = MFMA3216(ka1, qf[s + 1], s1);
            }
            __builtin_amdgcn_s_setprio(0);
        }
        f32x16 sc;
#pragma unroll
        for (int i = 0; i < 16; ++i) sc[i] = s0[i] + s1[i];

        // ---- defer-max trigger detect (block-uniform flag protocol) ----
        int need = 0;
#pragma unroll
        for (int i = 0; i < 16; ++i) need |= (sc[i] > mrun + 8.f) ? 1 : 0;
        if (__any(need)) { if (l == 0) flagLds = 1; }
        __syncthreads();                 // B1: flag combined; K-hat[t] reads done

        // ---- gll-stage K-hat[t+1] (overwrites tile t; lands by B2 drain) ----
        if (t + 1 < NT) {
#pragma unroll
            for (int i = 0; i < 8; ++i) {
                int c = i * 512 + tid;
                int row = c >> 5, ch = c & 31;
                GLL16(Hbase + (size_t)(kt + 128 + row) * 256 + ((ch ^ (row & 31)) * 8),
                      KhS + (size_t)(i * 4096 + w * 512));
            }
        }

        if (flagLds) {                   // rare, block-uniform
            float mx = sc[0];
#pragma unroll
            for (int i = 1; i < 16; ++i) mx = fmaxf(mx, sc[i]);
            mx = fmaxf(mx, __shfl_xor(mx, 32));
            if (l < 32) auxF[qh][kg][lm] = mx;
            __syncthreads();
            float mnew = fmaxf(fmaxf(auxF[qh][0][lm], auxF[qh][1][lm]),
                               fmaxf(auxF[qh][2][lm], auxF[qh][3][lm]));
            mnew = fmaxf(mrun, mnew);
            float corr = __expf(mrun - mnew);
            lsum *= corr;
            if (kg == 0 && l < 32) auxT[qh][lm] = corr;
            mrun = mnew;
            if (tid == 0) flagLds = 0;
            __syncthreads();
#pragma unroll
            for (int i = 0; i < 16; ++i) {
                int cr = (i & 3) + 8 * (i >> 2) + 4 * h;
                oac0[i] *= auxT[0][cr];
                oac1[i] *= auxT[1][cr];
            }
        }

        // ---- exp + P write (paired rows, conflict-free) ----
        {
            int pr = qh * 16 + (lm >> 1);
            f16* pw = PSh2 + (size_t)pr * 256 + 4 * h;
            int pcb = (lm & 1) * 16;
#pragma unroll
            for (int b4 = 0; b4 < 4; ++b4) {
                float p0 = __expf(sc[b4 * 4 + 0] - mrun);
                float p1 = __expf(sc[b4 * 4 + 1] - mrun);
                float p2 = __expf(sc[b4 * 4 + 2] - mrun);
                float p3 = __expf(sc[b4 * 4 + 3] - mrun);
                lsum += (p0 + p1) + (p2 + p3);
                f16x4 pv;
                pv[0] = (f16)p0; pv[1] = (f16)p1; pv[2] = (f16)p2; pv[3] = (f16)p3;
                *(f16x4*)(pw + ((pcb + 4 * kg + b4) ^ pr) * 8) = pv;
            }
        }

        __syncthreads();                 // B2: P visible; K-hat[t+1]+V[t] landed

        // ---- PV: O[64q x 32d] += P . V^T (A = P rows=q, B = V cols=d) ----
        {
            const f16* pb0 = PSh2 + (size_t)(lm >> 1) * 256;
            const f16* pb1 = PSh2 + (size_t)(16 + (lm >> 1)) * 256;
            const f16* vb  = VtS2 + (size_t)(w * 16 + (lm >> 1)) * 256;
            int kpa0 = (lm >> 1);
            int kpa1 = 16 + (lm >> 1);
            int kv   = (w * 16 + (lm >> 1)) & 31;
            int bq0  = (lm & 1) * 16;
            __builtin_amdgcn_s_setprio(1);
#pragma unroll
            for (int s = 0; s < 8; ++s) {
                int lc = bq0 + 2 * s + h;
                f16x8 pa0 = *(const f16x8*)(pb0 + (lc ^ kpa0) * 8);
                f16x8 pa1 = *(const f16x8*)(pb1 + (lc ^ kpa1) * 8);
                f16x8 vv  = *(const f16x8*)(vb  + (lc ^ kv) * 8);
                oac0 = MFMA3216(pa0, vv, oac0);
                oac1 = MFMA3216(pa1, vv, oac1);
            }
            __builtin_amdgcn_s_setprio(0);
        }

        // ---- gll-stage V[t+1], wave-sliced (only rows this wave reads) ----
        if (t + 1 < NT) {
#pragma unroll
            for (int i = 0; i < 8; ++i) {
                int j   = i * 64 + l;
                int prv = j >> 5, pc = j & 31;
                int kap = (w * 16 + prv) & 31;
                int lc  = pc ^ kap;
                int d   = w * 32 + prv * 2 + (lc >> 4);
                GLL16(Vbase + (size_t)d * S + (kt + 128) + ((lc & 15) * 8),
                      VtS2 + (size_t)(w * 4096 + i * 512));
            }
        }
    }

    // ---- epilogue: denominators across (kg,h) partials; write; no O merge ----
    lsum += __shfl_xor(lsum, 32);
    if (l < 32) auxF[qh][kg][lm] = lsum;
    __syncthreads();
    if (kg == 0 && l < 32) {
        float dsum = auxF[qh][0][lm] + auxF[qh][1][lm] +
                     auxF[qh][2][lm] + auxF[qh][3][lm];
        auxC[qh][lm] = 1.0f / dsum;
    }
    __syncthreads();

    float* Ob = Out + (size_t)(b * S + qbase) * 256 + w * 32 + lm;
#pragma unroll
    for (int i = 0; i < 16; ++i) {
        int cr = (i & 3) + 8 * (i >> 2) + 4 * h;
        Ob[(size_t)cr * 256]        = oac0[i] * auxC[0][cr];
        Ob[(size_t)(32 + cr) * 256] = oac1[i] * auxC[1][cr];
    }
}

// ---------------------------------------------------------------------------
extern "C" void kernel_launch(void* const* d_in, const int* in_sizes, int n_in,
                              void* d_out, int out_size, void* d_ws, size_t ws_size,
                              hipStream_t stream)
{
    const float* query = (const float*)d_in[0];
    const float* value = (const float*)d_in[1];
    const float* Wq    = (const float*)d_in[2];
    const float* bq    = (const float*)d_in[3];
    const float* Wk    = (const float*)d_in[4];
    const float* bk    = (const float*)d_in[5];
    const float* Wv    = (const float*)d_in[6];
    const float* bv    = (const float*)d_in[7];
    const float* Wr    = (const float*)d_in[8];
    const float* br    = (const float*)d_in[9];
    float* out = (float*)d_out;

    char* ws = (char*)d_ws;
    size_t off = 0;
    auto alloc = [&](size_t bytes) -> char* {
        char* p = ws + off;
        off += (bytes + 255) & ~(size_t)255;
        return p;
    };
    f16* WqT = (f16*)alloc((size_t)65536 * 2);
    f16* WkT = (f16*)alloc((size_t)65536 * 2);
    f16* WvT = (f16*)alloc((size_t)65536 * 2);
    f16* WrT = (f16*)alloc((size_t)65536 * 2);
    f16* Qf  = (f16*)alloc((size_t)NB * S * 256 * 2);
    f16* Kf  = (f16*)alloc((size_t)NB * S * 256 * 2);
    f16* Hf  = (f16*)alloc((size_t)NB * S * 256 * 2);
    f16* VtF = (f16*)alloc((size_t)NB * S * 256 * 2);
    (void)ws_size; (void)in_sizes; (void)n_in; (void)out_size;

    wconv4_kernel<<<1024, 256, 0, stream>>>(Wq, Wk, Wv, Wr, WqT, WkT, WvT, WrT);

    // Q = query @ Wq + bq           (f16 row-major)
    proj_kernel<0, 0><<<512, 256, 0, stream>>>(query, nullptr, WqT, bq, Qf);
    // K = value @ Wk + bk (row-major) and V^T = (value @ Wv + bv)^T, fused
    kvproj_kernel<<<512, 512, 0, stream>>>(value, WkT, WvT, bk, bv, Kf, VtF);
    // Khat = cos(K @ Wr + br)       (f16 row-major)
    proj_kernel<1, 1><<<512, 256, 0, stream>>>(nullptr, Kf, WrT, br, Hf);

    // flash attention: gll-staged K-hat AND V, conflict-free swizzles
    attn_kernel<<<256, 512, 0, stream>>>(Qf, Hf, VtF, out);
}

// Round 10
// 164.970 us; speedup vs baseline: 1.4211x; 1.0516x over previous
//
#include <hip/hip_runtime.h>
#include <hip/hip_bf16.h>

typedef _Float16 f16;
typedef _Float16 f16x8 __attribute__((ext_vector_type(8)));
typedef _Float16 f16x4 __attribute__((ext_vector_type(4)));
typedef float f32x4 __attribute__((ext_vector_type(4)));
typedef float f32x16 __attribute__((ext_vector_type(16)));

#define MFMA1632(a, b, c) __builtin_amdgcn_mfma_f32_16x16x32_f16(a, b, c, 0, 0, 0)
#define MFMA3216(a, b, c) __builtin_amdgcn_mfma_f32_32x32x16_f16(a, b, c, 0, 0, 0)

// async global->LDS, 16B per lane; LDS dest = wave-uniform base + lane*16
#define GLL16(g, l)                                                        \
    __builtin_amdgcn_global_load_lds(                                      \
        (const __attribute__((address_space(1))) void*)(g),                \
        (__attribute__((address_space(3))) void*)(l), 16, 0, 0)

static constexpr int S  = 4096;
static constexpr int NB = 4;    // batches

// ---------------------------------------------------------------------------
// Weight convert + transpose, all four weights in one launch.
// ---------------------------------------------------------------------------
__global__ void wconv4_kernel(const float* __restrict__ W0, const float* __restrict__ W1,
                              const float* __restrict__ W2, const float* __restrict__ W3,
                              f16* __restrict__ T0, f16* __restrict__ T1,
                              f16* __restrict__ T2, f16* __restrict__ T3) {
    int j = blockIdx.x >> 8;
    int k = blockIdx.x & 255;
    int n = threadIdx.x;
    const float* W = (j == 0) ? W0 : (j == 1) ? W1 : (j == 2) ? W2 : W3;
    f16*         T = (j == 0) ? T0 : (j == 1) ? T1 : (j == 2) ? T2 : T3;
    T[n * 256 + k] = (f16)W[k * 256 + n];
}

// ---------------------------------------------------------------------------
// Q projection GEMM (unchanged, proven).
// ---------------------------------------------------------------------------
__global__ __launch_bounds__(256) void qproj_kernel(
    const float* __restrict__ Af, const f16* __restrict__ Wt,
    const float* __restrict__ bias, f16* __restrict__ O)
{
    int mbase = blockIdx.x * 32;
    int tid = threadIdx.x;
    int w = tid >> 6, l = tid & 63;
    int lr = l & 15, lg = l >> 4;
    int nbase = w * 64;

    f32x4 acc[2][4];
#pragma unroll
    for (int mf = 0; mf < 2; ++mf)
#pragma unroll
        for (int nf = 0; nf < 4; ++nf) acc[mf][nf] = f32x4{0.f, 0.f, 0.f, 0.f};

#pragma unroll
    for (int ks = 0; ks < 8; ++ks) {
        int kof = ks * 32 + lg * 8;
        f16x8 a[2], b[4];
#pragma unroll
        for (int mf = 0; mf < 2; ++mf) {
            int row = mbase + mf * 16 + lr;
            const float4* p = (const float4*)(Af + row * 256 + kof);
            float4 x0 = p[0], x1 = p[1];
            f16x8 t;
            t[0] = (f16)x0.x; t[1] = (f16)x0.y; t[2] = (f16)x0.z; t[3] = (f16)x0.w;
            t[4] = (f16)x1.x; t[5] = (f16)x1.y; t[6] = (f16)x1.z; t[7] = (f16)x1.w;
            a[mf] = t;
        }
#pragma unroll
        for (int nf = 0; nf < 4; ++nf) {
            int col = nbase + nf * 16 + lr;
            b[nf] = *(const f16x8*)(Wt + col * 256 + kof);
        }
#pragma unroll
        for (int mf = 0; mf < 2; ++mf)
#pragma unroll
            for (int nf = 0; nf < 4; ++nf)
                acc[mf][nf] = MFMA1632(a[mf], b[nf], acc[mf][nf]);
    }

#pragma unroll
    for (int mf = 0; mf < 2; ++mf) {
#pragma unroll
        for (int nf = 0; nf < 4; ++nf) {
            int col = nbase + nf * 16 + lr;
            float bv = bias[col];
#pragma unroll
            for (int r = 0; r < 4; ++r) {
                int row = mbase + mf * 16 + lg * 4 + r;
                O[row * 256 + col] = (f16)(acc[mf][nf][r] + bv);
            }
        }
    }
}

// ---------------------------------------------------------------------------
// Fused K + V + K-hat projection from `value`.
//   Phase 1 (as kvproj): waves 0-3 compute K (32 rows x 256 cols) -> LDS;
//   waves 4-7 compute V -> global transposed VtF. Barrier.
//   Phase 2: all 8 waves compute Khat[32][256] = cos(K_lds @ Wr + br) -> Hf.
// Removes the Kf HBM round-trip and one kernel launch.
// ---------------------------------------------------------------------------
__global__ __launch_bounds__(512) void kvhproj_kernel(
    const float* __restrict__ Af,
    const f16* __restrict__ WkT, const f16* __restrict__ WvT,
    const f16* __restrict__ WrT,
    const float* __restrict__ bk, const float* __restrict__ bv,
    const float* __restrict__ br,
    f16* __restrict__ Hf, f16* __restrict__ VtF)
{
    __shared__ f16 KS[32][264];      // K tile, +16B row pad

    int mbase = blockIdx.x * 32;
    int tid = threadIdx.x;
    int w = tid >> 6, l = tid & 63;
    int lr = l & 15, lg = l >> 4;
    int path = w >> 2;               // 0: K->LDS, 1: V->global
    int nbase = (w & 3) * 64;
    const f16* Wt = path ? WvT : WkT;
    const float* bias = path ? bv : bk;

    f32x4 acc[2][4];
#pragma unroll
    for (int mf = 0; mf < 2; ++mf)
#pragma unroll
        for (int nf = 0; nf < 4; ++nf) acc[mf][nf] = f32x4{0.f, 0.f, 0.f, 0.f};

#pragma unroll
    for (int ks = 0; ks < 8; ++ks) {
        int kof = ks * 32 + lg * 8;
        f16x8 a[2], b[4];
#pragma unroll
        for (int mf = 0; mf < 2; ++mf) {
            int row = mbase + mf * 16 + lr;
            const float4* p = (const float4*)(Af + row * 256 + kof);
            float4 x0 = p[0], x1 = p[1];
            f16x8 t;
            t[0] = (f16)x0.x; t[1] = (f16)x0.y; t[2] = (f16)x0.z; t[3] = (f16)x0.w;
            t[4] = (f16)x1.x; t[5] = (f16)x1.y; t[6] = (f16)x1.z; t[7] = (f16)x1.w;
            a[mf] = t;
        }
#pragma unroll
        for (int nf = 0; nf < 4; ++nf) {
            int col = nbase + nf * 16 + lr;
            b[nf] = *(const f16x8*)(Wt + col * 256 + kof);
        }
#pragma unroll
        for (int mf = 0; mf < 2; ++mf)
#pragma unroll
            for (int nf = 0; nf < 4; ++nf)
                acc[mf][nf] = MFMA1632(a[mf], b[nf], acc[mf][nf]);
    }

#pragma unroll
    for (int mf = 0; mf < 2; ++mf) {
#pragma unroll
        for (int nf = 0; nf < 4; ++nf) {
            int col = nbase + nf * 16 + lr;
            float bv2 = bias[col];
            if (path == 0) {
#pragma unroll
                for (int r = 0; r < 4; ++r)
                    KS[mf * 16 + lg * 4 + r][col] = (f16)(acc[mf][nf][r] + bv2);
            } else {
                int bi = mbase >> 12;
                int s  = (mbase & (S - 1)) + mf * 16 + lg * 4;
                f16x4 v;
#pragma unroll
                for (int r = 0; r < 4; ++r) v[r] = (f16)(acc[mf][nf][r] + bv2);
                *(f16x4*)(VtF + ((bi * 256 + col) * S + s)) = v;
            }
        }
    }
    __syncthreads();

    // ---- Phase 2: Khat = cos(K @ Wr + br), all 8 waves, 32 cols each ----
    f32x4 acc2[2][2];
#pragma unroll
    for (int mf = 0; mf < 2; ++mf)
#pragma unroll
        for (int nf = 0; nf < 2; ++nf) acc2[mf][nf] = f32x4{0.f, 0.f, 0.f, 0.f};

#pragma unroll
    for (int ks = 0; ks < 8; ++ks) {
        int kof = ks * 32 + lg * 8;
        f16x8 a[2], b[2];
#pragma unroll
        for (int mf = 0; mf < 2; ++mf)
            a[mf] = *(const f16x8*)&KS[mf * 16 + lr][kof];
#pragma unroll
        for (int nf = 0; nf < 2; ++nf) {
            int col = w * 32 + nf * 16 + lr;
            b[nf] = *(const f16x8*)(WrT + col * 256 + kof);
        }
#pragma unroll
        for (int mf = 0; mf < 2; ++mf)
#pragma unroll
            for (int nf = 0; nf < 2; ++nf)
                acc2[mf][nf] = MFMA1632(a[mf], b[nf], acc2[mf][nf]);
    }

#pragma unroll
    for (int mf = 0; mf < 2; ++mf) {
#pragma unroll
        for (int nf = 0; nf < 2; ++nf) {
            int col = w * 32 + nf * 16 + lr;
            float bv2 = br[col];
#pragma unroll
            for (int r = 0; r < 4; ++r) {
                int row = mbase + mf * 16 + lg * 4 + r;
                Hf[row * 256 + col] = (f16)cosf(acc2[mf][nf][r] + bv2);
            }
        }
    }
}

// ---------------------------------------------------------------------------
// Flash attention, 32x32 MFMAs, KBLK=128, NT=32, counted-vmcnt barriers (T4).
//   All staging via global_load_lds (zero staging VGPRs), single-buffered.
//   K-hat [128][256]: phys chunk = logical ^ (row&31)  (st-32 pattern).
//   V^T   [256][128]: phys chunk = logical ^ (d&15)    (st-16 pattern).
//   P     [64][128] : phys chunk = logical ^ (q&15).
//   Barriers: B1 = __syncthreads (drains V[t], issued a full phase ago);
//   B2 = {lgkmcnt(0); s_barrier} (P visible; K̂[t+1] glls stay in flight);
//   B_end = {vmcnt(8); s_barrier} (K̂[t+1] landed; V[t+1] stays in flight).
//   QK: wave (qh=w>>2, kg=w&3): S^T[32k x 32q], lane owns one q-col ->
//   per-lane scalar softmax, block-uniform defer-max flag protocol.
//   PV: wave w owns d-slice w*32..+32 over both q-halves -> no O merge.
// Grid: 256 blocks.  bid&7 -> XCD; batch b = (bid>>1)&3 pins to 2 XCDs.
// ---------------------------------------------------------------------------
__global__ __launch_bounds__(512, 2) void attn_kernel(
    const f16* __restrict__ Qf, const f16* __restrict__ Hf,
    const f16* __restrict__ Vt, float* __restrict__ Out)
{
    __shared__ f16 KhS[128 * 256];      // 64 KB
    __shared__ f16 VtS[256 * 128];      // 64 KB
    __shared__ f16 PSh[64 * 128];       // 16 KB
    __shared__ float auxF[2][4][32];    // per-(qh,kg) row max / lsum partials
    __shared__ float auxT[2][32];       // trigger corr
    __shared__ float auxC[2][32];       // epilogue 1/denominator
    __shared__ int flagLds;

    int bid = blockIdx.x;
    int b   = (bid >> 1) & 3;
    int qi  = ((bid >> 3) << 1) | (bid & 1);
    int qbase = qi * 64;

    int tid = threadIdx.x;
    int w  = tid >> 6, l = tid & 63;
    int qh = w >> 2;            // QK q-half
    int kg = w & 3;             // QK key-slice
    int lm = l & 31;
    int h  = l >> 5;

    const f16* Hbase = Hf + (size_t)b * S * 256;
    const f16* Vbase = Vt + (size_t)b * 256 * S;

    // Q fragments (B-operand of S^T): q-col = qbase + qh*32 + lm  (64 VGPR)
    f16x8 qf[16];
    {
        const f16* qp = Qf + (size_t)(b * S + qbase + qh * 32 + lm) * 256 + h * 8;
#pragma unroll
        for (int s = 0; s < 16; ++s) qf[s] = *(const f16x8*)(qp + s * 16);
    }

    f32x16 oac0, oac1;
#pragma unroll
    for (int i = 0; i < 16; ++i) { oac0[i] = 0.f; oac1[i] = 0.f; }
    float mrun = -1e30f, lsum = 0.f;

    if (tid == 0) flagLds = 0;

    // ---- prologue: gll-stage K-hat[0] (all threads) and V[0] (wave-sliced)
#pragma unroll
    for (int i = 0; i < 8; ++i) {
        int c = i * 512 + tid;
        int row = c >> 5, ch = c & 31;
        GLL16(Hbase + (size_t)row * 256 + ((ch ^ (row & 31)) * 8),
              KhS + (size_t)(i * 4096 + w * 512));
    }
#pragma unroll
    for (int i = 0; i < 8; ++i) {
        int d  = w * 32 + i * 4 + (l >> 4);
        int cp = l & 15;
        GLL16(Vbase + (size_t)d * S + ((cp ^ (d & 15)) * 8),
              VtS + (size_t)(w * 4096 + i * 512));
    }
    __syncthreads();    // full drain -> tile 0 landed

    const int NT = S / 128;     // 32 key-tiles
    for (int t = 0; t < NT; ++t) {
        int kt = t * 128;

        // ---- QK: S^T = Khat_slice . Q  (A rows = keys, B cols = q) ----
        f32x16 s0, s1;
#pragma unroll
        for (int i = 0; i < 16; ++i) { s0[i] = 0.f; s1[i] = 0.f; }
        {
            const f16* kb = KhS + (size_t)(kg * 32 + lm) * 256;
            __builtin_amdgcn_s_setprio(1);
#pragma unroll
            for (int s = 0; s < 16; s += 2) {
                f16x8 ka0 = *(const f16x8*)(kb + ((2 * s + h) ^ lm) * 8);
                f16x8 ka1 = *(const f16x8*)(kb + ((2 * s + 2 + h) ^ lm) * 8);
                s0 = MFMA3216(ka0, qf[s], s0);
                s1 = MFMA3216(ka1, qf[s + 1], s1);
            }
            __builtin_amdgcn_s_setprio(0);
        }
        f32x16 sc;
#pragma unroll
        for (int i = 0; i < 16; ++i) sc[i] = s0[i] + s1[i];

        // ---- defer-max trigger detect (block-uniform flag protocol) ----
        int need = 0;
#pragma unroll
        for (int i = 0; i < 16; ++i) need |= (sc[i] > mrun + 8.f) ? 1 : 0;
        if (__any(need)) { if (l == 0) flagLds = 1; }
        __syncthreads();   // B1: flag visible; K-hat[t] reads done; V[t] landed

        // ---- gll-stage K-hat[t+1] (overwrite safe; lands by B_end) ----
        if (t + 1 < NT) {
#pragma unroll
            for (int i = 0; i < 8; ++i) {
                int c = i * 512 + tid;
                int row = c >> 5, ch = c & 31;
                GLL16(Hbase + (size_t)(kt + 128 + row) * 256 + ((ch ^ (row & 31)) * 8),
                      KhS + (size_t)(i * 4096 + w * 512));
            }
        }

        if (flagLds) {                   // rare, block-uniform
            float mx = sc[0];
#pragma unroll
            for (int i = 1; i < 16; ++i) mx = fmaxf(mx, sc[i]);
            mx = fmaxf(mx, __shfl_xor(mx, 32));
            if (l < 32) auxF[qh][kg][lm] = mx;
            __syncthreads();
            float mnew = fmaxf(fmaxf(auxF[qh][0][lm], auxF[qh][1][lm]),
                               fmaxf(auxF[qh][2][lm], auxF[qh][3][lm]));
            mnew = fmaxf(mrun, mnew);
            float corr = __expf(mrun - mnew);
            lsum *= corr;
            if (kg == 0 && l < 32) auxT[qh][lm] = corr;
            mrun = mnew;
            if (tid == 0) flagLds = 0;
            __syncthreads();
#pragma unroll
            for (int i = 0; i < 16; ++i) {
                int cr = (i & 3) + 8 * (i >> 2) + 4 * h;
                oac0[i] *= auxT[0][cr];
                oac1[i] *= auxT[1][cr];
            }
        }

        // ---- exp + P write (16-chunk rows, key q&15 -> conflict-free) ----
        {
            f16* pw = PSh + (size_t)(qh * 32 + lm) * 128;
            int key = lm & 15;
#pragma unroll
            for (int b4 = 0; b4 < 4; ++b4) {
                float p0 = __expf(sc[b4 * 4 + 0] - mrun);
                float p1 = __expf(sc[b4 * 4 + 1] - mrun);
                float p2 = __expf(sc[b4 * 4 + 2] - mrun);
                float p3 = __expf(sc[b4 * 4 + 3] - mrun);
                lsum += (p0 + p1) + (p2 + p3);
                f16x4 pv;
                pv[0] = (f16)p0; pv[1] = (f16)p1; pv[2] = (f16)p2; pv[3] = (f16)p3;
                *(f16x4*)(pw + ((4 * kg + b4) ^ key) * 8 + 4 * h) = pv;
            }
        }

        // B2: P visible to all waves; K-hat[t+1] glls NOT drained
        asm volatile("s_waitcnt lgkmcnt(0)" ::: "memory");
        __builtin_amdgcn_s_barrier();

        // ---- PV: O[64q x 32d] += P . V^T (A = P rows=q, B = V cols=d) ----
        {
            const f16* pb0 = PSh + (size_t)lm * 128;
            const f16* pb1 = PSh + (size_t)(32 + lm) * 128;
            const f16* vb  = VtS + (size_t)(w * 32 + lm) * 128;
            int kp = lm & 15;
            __builtin_amdgcn_s_setprio(1);
#pragma unroll
            for (int s = 0; s < 8; ++s) {
                int lc = 2 * s + h;
                f16x8 pa0 = *(const f16x8*)(pb0 + (lc ^ kp) * 8);
                f16x8 pa1 = *(const f16x8*)(pb1 + (lc ^ kp) * 8);
                f16x8 vv  = *(const f16x8*)(vb  + (lc ^ kp) * 8);
                oac0 = MFMA3216(pa0, vv, oac0);
                oac1 = MFMA3216(pa1, vv, oac1);
            }
            __builtin_amdgcn_s_setprio(0);
        }

        // ---- gll-stage V[t+1], wave-sliced (only rows this wave reads) ----
        if (t + 1 < NT) {
#pragma unroll
            for (int i = 0; i < 8; ++i) {
                int d  = w * 32 + i * 4 + (l >> 4);
                int cp = l & 15;
                GLL16(Vbase + (size_t)d * S + (kt + 128) + ((cp ^ (d & 15)) * 8),
                      VtS + (size_t)(w * 4096 + i * 512));
            }
        }

        // B_end: wait K-hat[t+1] (oldest 8) landed; V[t+1] (newest 8) in flight
        asm volatile("s_waitcnt vmcnt(8)" ::: "memory");
        __builtin_amdgcn_s_barrier();
    }

    // ---- epilogue: denominators across (kg,h) partials; write; no O merge ----
    lsum += __shfl_xor(lsum, 32);
    if (l < 32) auxF[qh][kg][lm] = lsum;
    __syncthreads();
    if (kg == 0 && l < 32) {
        float dsum = auxF[qh][0][lm] + auxF[qh][1][lm] +
                     auxF[qh][2][lm] + auxF[qh][3][lm];
        auxC[qh][lm] = 1.0f / dsum;
    }
    __syncthreads();

    float* Ob = Out + (size_t)(b * S + qbase) * 256 + w * 32 + lm;
#pragma unroll
    for (int i = 0; i < 16; ++i) {
        int cr = (i & 3) + 8 * (i >> 2) + 4 * h;
        Ob[(size_t)cr * 256]        = oac0[i] * auxC[0][cr];
        Ob[(size_t)(32 + cr) * 256] = oac1[i] * auxC[1][cr];
    }
}

// ---------------------------------------------------------------------------
extern "C" void kernel_launch(void* const* d_in, const int* in_sizes, int n_in,
                              void* d_out, int out_size, void* d_ws, size_t ws_size,
                              hipStream_t stream)
{
    const float* query = (const float*)d_in[0];
    const float* value = (const float*)d_in[1];
    const float* Wq    = (const float*)d_in[2];
    const float* bq    = (const float*)d_in[3];
    const float* Wk    = (const float*)d_in[4];
    const float* bk    = (const float*)d_in[5];
    const float* Wv    = (const float*)d_in[6];
    const float* bv    = (const float*)d_in[7];
    const float* Wr    = (const float*)d_in[8];
    const float* br    = (const float*)d_in[9];
    float* out = (float*)d_out;

    char* ws = (char*)d_ws;
    size_t off = 0;
    auto alloc = [&](size_t bytes) -> char* {
        char* p = ws + off;
        off += (bytes + 255) & ~(size_t)255;
        return p;
    };
    f16* WqT = (f16*)alloc((size_t)65536 * 2);
    f16* WkT = (f16*)alloc((size_t)65536 * 2);
    f16* WvT = (f16*)alloc((size_t)65536 * 2);
    f16* WrT = (f16*)alloc((size_t)65536 * 2);
    f16* Qf  = (f16*)alloc((size_t)NB * S * 256 * 2);
    f16* Hf  = (f16*)alloc((size_t)NB * S * 256 * 2);
    f16* VtF = (f16*)alloc((size_t)NB * S * 256 * 2);
    (void)ws_size; (void)in_sizes; (void)n_in; (void)out_size;

    wconv4_kernel<<<1024, 256, 0, stream>>>(Wq, Wk, Wv, Wr, WqT, WkT, WvT, WrT);

    // Q = query @ Wq + bq           (f16 row-major)
    qproj_kernel<<<512, 256, 0, stream>>>(query, WqT, bq, Qf);
    // K, V, and Khat = cos(K @ Wr + br), fused (no Kf round-trip)
    kvhproj_kernel<<<512, 512, 0, stream>>>(value, WkT, WvT, WrT, bk, bv, br, Hf, VtF);

    // flash attention: counted-vmcnt barriers, conflict-free swizzles
    attn_kernel<<<256, 512, 0, stream>>>(Qf, Hf, VtF, out);
}